// Round 6
// baseline (238.961 us; speedup 1.0000x reference)
//
#include <hip/hip_runtime.h>
#include <math.h>

#define Bn 8
#define Cn 512
#define Tn 1024

typedef __attribute__((ext_vector_type(8))) short bf16x8;
typedef __attribute__((ext_vector_type(4))) float f32x4;

__device__ __forceinline__ unsigned short f2bf(float f) {
  unsigned int u = __builtin_bit_cast(unsigned int, f);
  u = (u + 0x7FFFu + ((u >> 16) & 1u)) >> 16;
  return (unsigned short)u;
}

__device__ __forceinline__ unsigned int cvtpk_bf16(float lo, float hi) {
  unsigned int r;
  asm("v_cvt_pk_bf16_f32 %0, %1, %2" : "=v"(r) : "v"(lo), "v"(hi));
  return r;
}

typedef __attribute__((address_space(1))) const unsigned int GU32;
typedef __attribute__((address_space(3))) unsigned int LU32;
__device__ __forceinline__ void gld16(const unsigned short* g, unsigned short* l) {
  __builtin_amdgcn_global_load_lds((GU32*)g, (LU32*)l, 16, 0, 0);
}

// Stage a 128-row x 64-col bf16 tile into linear LDS [128][64] with
// XOR-swizzled columns: LDS[row][c16] holds G[row][c16 ^ (row&7)] (16B units).
__device__ __forceinline__ void stage128x64(const unsigned short* __restrict__ src,
                                            size_t row_stride, unsigned short* lds, int tid) {
  const int w = tid >> 6;
  const int row = tid >> 3;
  const int sc = (tid & 7) ^ ((tid >> 3) & 7);
#pragma unroll
  for (int c = 0; c < 4; ++c)
    gld16(src + (size_t)(c * 32 + row) * row_stride + sc * 8,
          (unsigned short*)((char*)lds + c * 4096 + w * 1024));
}

// ---------------------------------------------------------------------------
// GroupNorm -> bf16 transposed xn_t [b][t][c]
// ---------------------------------------------------------------------------
__global__ __launch_bounds__(256) void gn_kernel(const float* __restrict__ x,
                                                 const float* __restrict__ gw,
                                                 const float* __restrict__ gb,
                                                 unsigned short* __restrict__ xn_t) {
  const int blk = blockIdx.x;
  const int b = blk >> 5, g = blk & 31;
  const size_t base = ((size_t)b * Cn + (size_t)g * 16) * Tn;
  const float4* __restrict__ xin = (const float4*)(x + base);
  const int tid = threadIdx.x;

  float vv[16][4];
  float sum = 0.f, sq = 0.f;
#pragma unroll
  for (int k = 0; k < 16; ++k) {
    const float4 t4 = xin[tid + (k << 8)];
    vv[k][0] = t4.x; vv[k][1] = t4.y; vv[k][2] = t4.z; vv[k][3] = t4.w;
    sum += t4.x + t4.y + t4.z + t4.w;
    sq += t4.x * t4.x + t4.y * t4.y + t4.z * t4.z + t4.w * t4.w;
  }

  __shared__ float rs[8];
  const int lane = tid & 63, wv = tid >> 6;
#pragma unroll
  for (int off = 32; off > 0; off >>= 1) {
    sum += __shfl_down(sum, off);
    sq += __shfl_down(sq, off);
  }
  if (lane == 0) { rs[wv] = sum; rs[4 + wv] = sq; }
  __syncthreads();
  const float ts = rs[0] + rs[1] + rs[2] + rs[3];
  const float tq = rs[4] + rs[5] + rs[6] + rs[7];
  const float mean = ts * (1.f / 16384.f);
  const float var = tq * (1.f / 16384.f) - mean * mean;
  const float rstd = rsqrtf(var + 1e-5f);

  float aa[16], bb[16];
#pragma unroll
  for (int k = 0; k < 16; ++k) {
    aa[k] = rstd * gw[g * 16 + k];
    bb[k] = gb[g * 16 + k] - mean * aa[k];
  }

#pragma unroll
  for (int j = 0; j < 4; ++j) {
    const int t = tid * 4 + j;
    unsigned int pk[8];
#pragma unroll
    for (int k2 = 0; k2 < 8; ++k2) {
      const unsigned int lo = f2bf(vv[2 * k2][j] * aa[2 * k2] + bb[2 * k2]);
      const unsigned int hi = f2bf(vv[2 * k2 + 1][j] * aa[2 * k2 + 1] + bb[2 * k2 + 1]);
      pk[k2] = lo | (hi << 16);
    }
    unsigned short* dst = xn_t + ((size_t)(b * Tn + t)) * Cn + g * 16;
    *(uint4*)dst = make_uint4(pk[0], pk[1], pk[2], pk[3]);
    *((uint4*)dst + 1) = make_uint4(pk[4], pk[5], pk[6], pk[7]);
  }
}

__global__ __launch_bounds__(256) void cvt_kernel(const float* __restrict__ src,
                                                  unsigned short* __restrict__ dst, int n4) {
  const int i = blockIdx.x * 256 + threadIdx.x;
  if (i < n4) {
    const float4 f = ((const float4*)src)[i];
    uint2 o;
    o.x = (unsigned int)f2bf(f.x) | ((unsigned int)f2bf(f.y) << 16);
    o.y = (unsigned int)f2bf(f.z) | ((unsigned int)f2bf(f.w) << 16);
    ((uint2*)dst)[i] = o;
  }
}

// ---------------------------------------------------------------------------
// QKV GEMM, LDS-staged 128x128 tile, BK=64 double-buffered. Flat grid 768,
// XCD-swizzled: b = id&7. q scaled by 0.125*log2(e) (attn runs in exp2 domain).
// V bounced through LDS for coalesced [c][t] stores.
// ---------------------------------------------------------------------------
__global__ __launch_bounds__(256, 2) void qkv_gemm(const unsigned short* __restrict__ Wb,
                                                   const unsigned short* __restrict__ Xb,
                                                   const float* __restrict__ bias,
                                                   unsigned short* __restrict__ q_t,
                                                   unsigned short* __restrict__ k_t,
                                                   unsigned short* __restrict__ v_t) {
  __shared__ unsigned short As[2][8192];
  __shared__ unsigned short Bs[2][8192];
  const int id = blockIdx.x;
  const int b = id & 7;
  const int inner = id >> 3;           // 0..95
  const int bx = inner % 12, by = inner / 12;
  const int o0 = bx * 128, t0 = by * 128;
  const int tid = threadIdx.x, lane = tid & 63, w = tid >> 6;
  const int wr = w >> 1, wc = w & 1;
  const int ln = lane & 15, g16 = lane >> 4;
  const unsigned short* __restrict__ X = Xb + (size_t)b * Tn * Cn;
  const unsigned short* __restrict__ Wt = Wb + (size_t)o0 * 512;
  const unsigned short* __restrict__ Xt = X + (size_t)t0 * 512;

  f32x4 acc[4][4];
#pragma unroll
  for (int mt = 0; mt < 4; ++mt)
#pragma unroll
    for (int nt = 0; nt < 4; ++nt) acc[mt][nt] = (f32x4){0.f, 0.f, 0.f, 0.f};

  stage128x64(Wt, 512, &As[0][0], tid);
  stage128x64(Xt, 512, &Bs[0][0], tid);
  __syncthreads();

  int buf = 0;
  for (int k0 = 0; k0 < 512; k0 += 64) {
    if (k0 + 64 < 512) {
      stage128x64(Wt + k0 + 64, 512, &As[buf ^ 1][0], tid);
      stage128x64(Xt + k0 + 64, 512, &Bs[buf ^ 1][0], tid);
    }
    const char* Ab = (const char*)&As[buf][0];
    const char* Bb = (const char*)&Bs[buf][0];
    bf16x8 af[4][2], bfr[4][2];
#pragma unroll
    for (int mt = 0; mt < 4; ++mt)
#pragma unroll
      for (int kk = 0; kk < 2; ++kk) {
        const int row = wr * 64 + mt * 16 + ln;
        const int c16 = ((kk << 2) | g16) ^ (ln & 7);
        af[mt][kk] = *(const bf16x8*)(Ab + row * 128 + (c16 << 4));
      }
#pragma unroll
    for (int nt = 0; nt < 4; ++nt)
#pragma unroll
      for (int kk = 0; kk < 2; ++kk) {
        const int row = wc * 64 + nt * 16 + ln;
        const int c16 = ((kk << 2) | g16) ^ (ln & 7);
        bfr[nt][kk] = *(const bf16x8*)(Bb + row * 128 + (c16 << 4));
      }
#pragma unroll
    for (int kk = 0; kk < 2; ++kk)
#pragma unroll
      for (int mt = 0; mt < 4; ++mt)
#pragma unroll
        for (int nt = 0; nt < 4; ++nt)
          acc[mt][nt] =
              __builtin_amdgcn_mfma_f32_16x16x32_bf16(af[mt][kk], bfr[nt][kk], acc[mt][nt], 0, 0, 0);
    __syncthreads();
    buf ^= 1;
  }

  const int o_base = o0 + wr * 64, t_base = t0 + wc * 64;
  const int partw = (o_base >> 6) % 3;          // whole 64-row half is one part
  const int bh = b * 8 + o_base / 192;
  unsigned short (*Vlds)[136] = (unsigned short (*)[136])(&As[0][0]);

  if (partw < 2) {
    unsigned short* qk = (partw == 0 ? q_t : k_t) + (size_t)bh * 65536;
    // q carries 0.125 (attn scale) * log2(e) (exp2-domain softmax)
    const float sc = (partw == 0) ? 0.18033688f : 1.0f;
#pragma unroll
    for (int mt = 0; mt < 4; ++mt) {
      const int ob16 = o_base + mt * 16;
      float bv[4];
#pragma unroll
      for (int r = 0; r < 4; ++r) bv[r] = bias[ob16 + g16 * 4 + r];
#pragma unroll
      for (int nt = 0; nt < 4; ++nt) {
        const int t = t_base + nt * 16 + ln;
        const float v0 = (acc[mt][nt][0] + bv[0]) * sc;
        const float v1 = (acc[mt][nt][1] + bv[1]) * sc;
        const float v2 = (acc[mt][nt][2] + bv[2]) * sc;
        const float v3 = (acc[mt][nt][3] + bv[3]) * sc;
        uint2 pk;
        pk.x = (unsigned int)f2bf(v0) | ((unsigned int)f2bf(v1) << 16);
        pk.y = (unsigned int)f2bf(v2) | ((unsigned int)f2bf(v3) << 16);
        *(uint2*)(qk + (size_t)t * 64 + mt * 16 + g16 * 4) = pk;
      }
    }
  } else {
    // V: write [c][t] tile into LDS (c = mt*16+g16*4+r in [0,64), t local)
#pragma unroll
    for (int mt = 0; mt < 4; ++mt) {
      float bv[4];
#pragma unroll
      for (int r = 0; r < 4; ++r) bv[r] = bias[o_base + mt * 16 + g16 * 4 + r];
#pragma unroll
      for (int nt = 0; nt < 4; ++nt)
#pragma unroll
        for (int r = 0; r < 4; ++r)
          Vlds[mt * 16 + g16 * 4 + r][wc * 64 + nt * 16 + ln] = f2bf(acc[mt][nt][r] + bv[r]);
    }
  }
  __syncthreads();
  const int bxm = bx % 3;     // 1 -> wr=0 half is V; 2 -> wr=1 half is V; 0 -> none
  if (bxm) {
    const int o_first = o0 + (bxm - 1) * 64;    // = 192*hh + 128, so c base = 0
    unsigned short* vdst = v_t + (size_t)(b * 8 + o_first / 192) * 65536;
    const int c = tid >> 2, tseg = (tid & 3) << 5;
    const unsigned short* src = &Vlds[c][tseg];
    unsigned short* p = vdst + (size_t)c * Tn + t0 + tseg;
    const uint4 d0 = *(const uint4*)(src);
    const uint4 d1 = *(const uint4*)(src + 8);
    const uint4 d2 = *(const uint4*)(src + 16);
    const uint4 d3 = *(const uint4*)(src + 24);
    *(uint4*)(p) = d0;
    *(uint4*)(p + 8) = d1;
    *(uint4*)(p + 16) = d2;
    *(uint4*)(p + 24) = d3;
  }
}

// ---------------------------------------------------------------------------
// Flash attention, SWAPPED QK^T (T12 structure): S^T = mfma(K,Q) puts a full
// 16-value P-slice of row t=lane&15 in each lane -> per-lane scalar m/l,
// 2 shuffles per reduction, cvt_pk packing, 4 ds_write_b64 + 2 ds_read_b128.
// 1024 blocks x 4 INDEPENDENT waves (16 t-rows each, no barriers).
// exp2 domain (scale folded into q). Defer-max THR=11 (=8*log2e).
// ---------------------------------------------------------------------------
__global__ __launch_bounds__(256, 4) void attn_kernel(const unsigned short* __restrict__ q_t,
                                                      const unsigned short* __restrict__ k_t,
                                                      const unsigned short* __restrict__ v_t,
                                                      unsigned short* __restrict__ h_t) {
  // per-wave P buffer: [16 t][64 s] bf16, XOR-swizzled 16B units
  __shared__ __align__(16) unsigned short P_lds[4][1024];
  const int id = blockIdx.x;
  const int xcd = id & 7, qq = id >> 3;           // 16 t-chunks x 8 heads per XCD
  const int bh = ((qq >> 4) << 3) | xcd;          // same head -> same XCD
  const int tc = qq & 15;
  const int tid = threadIdx.x, lane = tid & 63, w = tid >> 6;
  const int t_wave = tc * 64 + w * 16;
  const int ln = lane & 15, g16 = lane >> 4, g8 = g16 * 8;
  const unsigned short* __restrict__ qbase = q_t + (size_t)bh * 65536;
  const unsigned short* __restrict__ kbase = k_t + (size_t)bh * 65536;
  const unsigned short* __restrict__ vbase = v_t + (size_t)bh * 65536;
  char* __restrict__ Pb = (char*)P_lds[w];

  // LDS byte offsets (swizzle: 16B-unit index ^= (t&7), t = ln)
  int wr_off[4], rd_off[2];
#pragma unroll
  for (int ns = 0; ns < 4; ++ns)
    wr_off[ns] = ln * 128 + ((((ns << 1) | (g16 >> 1)) ^ (ln & 7)) << 4) + ((g16 & 1) << 3);
#pragma unroll
  for (int kb = 0; kb < 2; ++kb)
    rd_off[kb] = ln * 128 + ((((kb << 2) | g16) ^ (ln & 7)) << 4);

  // Q fragment (B-operand): row t = t_wave + ln, k-window = kb*32 + g8
  bf16x8 qf[2];
#pragma unroll
  for (int kb = 0; kb < 2; ++kb)
    qf[kb] = *(const bf16x8*)(qbase + (size_t)(t_wave + ln) * 64 + kb * 32 + g8);

  f32x4 o_acc[4];
#pragma unroll
  for (int nc = 0; nc < 4; ++nc) o_acc[nc] = (f32x4){0.f, 0.f, 0.f, 0.f};
  float m_run = -1e30f, l_run = 0.f;

  for (int st = 0; st < 16; ++st) {
    const int s0 = st << 6;
    // K fragments (A-operand): row s = s0 + ns*16 + ln
    bf16x8 kf[4][2];
#pragma unroll
    for (int ns = 0; ns < 4; ++ns)
#pragma unroll
      for (int kb = 0; kb < 2; ++kb)
        kf[ns][kb] = *(const bf16x8*)(kbase + (size_t)(s0 + ns * 16 + ln) * 64 + kb * 32 + g8);

    f32x4 sacc[4];
#pragma unroll
    for (int ns = 0; ns < 4; ++ns) sacc[ns] = (f32x4){0.f, 0.f, 0.f, 0.f};

    __builtin_amdgcn_s_setprio(1);
#pragma unroll
    for (int kb = 0; kb < 2; ++kb)
#pragma unroll
      for (int ns = 0; ns < 4; ++ns)
        sacc[ns] = __builtin_amdgcn_mfma_f32_16x16x32_bf16(kf[ns][kb], qf[kb], sacc[ns], 0, 0, 0);
    __builtin_amdgcn_s_setprio(0);
    // lane now holds S^T[s = s0 + 16ns + 4g16 + r][t = t_wave + ln]

    // V loads issued early (land under softmax VALU chain)
    bf16x8 vf[4][2];
#pragma unroll
    for (int nc = 0; nc < 4; ++nc)
#pragma unroll
      for (int kb = 0; kb < 2; ++kb)
        vf[nc][kb] = *(const bf16x8*)(vbase + (size_t)(nc * 16 + ln) * Tn + s0 + kb * 32 + g8);

    // row max: 15 in-lane fmax + 2 shuffles (exp2 domain)
    float m = sacc[0][0];
#pragma unroll
    for (int ns = 0; ns < 4; ++ns)
#pragma unroll
      for (int r = 0; r < 4; ++r) m = fmaxf(m, sacc[ns][r]);
    m = fmaxf(m, __shfl_xor(m, 16));
    m = fmaxf(m, __shfl_xor(m, 32));

    if (__any((m > m_run + 11.f) ? 1 : 0)) {
      const float mnew = fmaxf(m_run, m);
      const float al = __builtin_amdgcn_exp2f(m_run - mnew);
      m_run = mnew;
      l_run *= al;
      float al4[4];
#pragma unroll
      for (int r = 0; r < 4; ++r) al4[r] = __shfl(al, (g16 << 2) + r);
#pragma unroll
      for (int nc = 0; nc < 4; ++nc)
#pragma unroll
        for (int r = 0; r < 4; ++r) o_acc[nc][r] *= al4[r];
    }

    // p = exp2(S - m_run) in place; per-lane sum
    float rsum = 0.f;
#pragma unroll
    for (int ns = 0; ns < 4; ++ns) {
#pragma unroll
      for (int r = 0; r < 4; ++r) {
        sacc[ns][r] = __builtin_amdgcn_exp2f(sacc[ns][r] - m_run);
        rsum += sacc[ns][r];
      }
    }
    rsum += __shfl_xor(rsum, 16);
    rsum += __shfl_xor(rsum, 32);
    l_run += rsum;

    // pack P (bf16) and exchange through swizzled LDS
#pragma unroll
    for (int ns = 0; ns < 4; ++ns) {
      uint2 pk2;
      pk2.x = cvtpk_bf16(sacc[ns][0], sacc[ns][1]);
      pk2.y = cvtpk_bf16(sacc[ns][2], sacc[ns][3]);
      *(uint2*)(Pb + wr_off[ns]) = pk2;
    }
    bf16x8 pf[2];
#pragma unroll
    for (int kb = 0; kb < 2; ++kb) pf[kb] = *(const bf16x8*)(Pb + rd_off[kb]);

    __builtin_amdgcn_s_setprio(1);
#pragma unroll
    for (int kb = 0; kb < 2; ++kb)
#pragma unroll
      for (int nc = 0; nc < 4; ++nc)
        o_acc[nc] = __builtin_amdgcn_mfma_f32_16x16x32_bf16(pf[kb], vf[nc][kb], o_acc[nc], 0, 0, 0);
    __builtin_amdgcn_s_setprio(0);
  }

  // epilogue: O /= l (l lives at lane ln = t_local), store h_t[b][t][hh*64+c]
  const float rl = 1.f / l_run;
  float rl4[4];
#pragma unroll
  for (int r = 0; r < 4; ++r) rl4[r] = __shfl(rl, (g16 << 2) + r);
  const int b = bh >> 3, hh = bh & 7;
  unsigned short* __restrict__ hb = h_t + (size_t)b * Tn * Cn + hh * 64;
#pragma unroll
  for (int nc = 0; nc < 4; ++nc) {
    const int c = nc * 16 + ln;
#pragma unroll
    for (int r = 0; r < 4; ++r) {
      const int t = t_wave + g16 * 4 + r;
      hb[(size_t)t * Cn + c] = f2bf(o_acc[nc][r] * rl4[r]);
    }
  }
}

// ---------------------------------------------------------------------------
// Proj GEMM + bias + residual, LDS-staged. Flat grid 256, XCD-swizzled.
// ---------------------------------------------------------------------------
__global__ __launch_bounds__(256, 2) void proj_gemm(const unsigned short* __restrict__ Wb,
                                                    const unsigned short* __restrict__ Hb,
                                                    const float* __restrict__ pbias,
                                                    const float* __restrict__ x,
                                                    float* __restrict__ out) {
  __shared__ unsigned short As[2][8192];
  __shared__ unsigned short Bs[2][8192];
  const int id = blockIdx.x;
  const int b = id & 7;
  const int inner = id >> 3;            // 0..31
  const int bx = inner & 3, by = inner >> 2;
  const int o0 = bx * 128, t0 = by * 128;
  const int tid = threadIdx.x, lane = tid & 63, w = tid >> 6;
  const int wr = w >> 1, wc = w & 1;
  const int ln = lane & 15, g16 = lane >> 4;
  const unsigned short* __restrict__ H = Hb + (size_t)b * Tn * Cn;
  const unsigned short* __restrict__ Wt = Wb + (size_t)o0 * 512;
  const unsigned short* __restrict__ Ht = H + (size_t)t0 * 512;

  f32x4 acc[4][4];
#pragma unroll
  for (int mt = 0; mt < 4; ++mt)
#pragma unroll
    for (int nt = 0; nt < 4; ++nt) acc[mt][nt] = (f32x4){0.f, 0.f, 0.f, 0.f};

  stage128x64(Wt, 512, &As[0][0], tid);
  stage128x64(Ht, 512, &Bs[0][0], tid);
  __syncthreads();

  int buf = 0;
  for (int k0 = 0; k0 < 512; k0 += 64) {
    if (k0 + 64 < 512) {
      stage128x64(Wt + k0 + 64, 512, &As[buf ^ 1][0], tid);
      stage128x64(Ht + k0 + 64, 512, &Bs[buf ^ 1][0], tid);
    }
    const char* Ab = (const char*)&As[buf][0];
    const char* Bb = (const char*)&Bs[buf][0];
    bf16x8 af[4][2], bfr[4][2];
#pragma unroll
    for (int mt = 0; mt < 4; ++mt)
#pragma unroll
      for (int kk = 0; kk < 2; ++kk) {
        const int row = wr * 64 + mt * 16 + ln;
        const int c16 = ((kk << 2) | g16) ^ (ln & 7);
        af[mt][kk] = *(const bf16x8*)(Ab + row * 128 + (c16 << 4));
      }
#pragma unroll
    for (int nt = 0; nt < 4; ++nt)
#pragma unroll
      for (int kk = 0; kk < 2; ++kk) {
        const int row = wc * 64 + nt * 16 + ln;
        const int c16 = ((kk << 2) | g16) ^ (ln & 7);
        bfr[nt][kk] = *(const bf16x8*)(Bb + row * 128 + (c16 << 4));
      }
#pragma unroll
    for (int kk = 0; kk < 2; ++kk)
#pragma unroll
      for (int mt = 0; mt < 4; ++mt)
#pragma unroll
        for (int nt = 0; nt < 4; ++nt)
          acc[mt][nt] =
              __builtin_amdgcn_mfma_f32_16x16x32_bf16(af[mt][kk], bfr[nt][kk], acc[mt][nt], 0, 0, 0);
    __syncthreads();
    buf ^= 1;
  }

  const int o_base = o0 + wr * 64, t_base = t0 + wc * 64;
#pragma unroll
  for (int mt = 0; mt < 4; ++mt) {
    const int ob = o_base + mt * 16 + g16 * 4;
    float pb[4];
#pragma unroll
    for (int r = 0; r < 4; ++r) pb[r] = pbias[ob + r];
#pragma unroll
    for (int nt = 0; nt < 4; ++nt) {
      const int t = t_base + nt * 16 + ln;
#pragma unroll
      for (int r = 0; r < 4; ++r) {
        const size_t idx = (size_t)b * Cn * Tn + (size_t)(ob + r) * Tn + t;
        out[idx] = acc[mt][nt][r] + pb[r] + x[idx];
      }
    }
  }
}

// ---------------------------------------------------------------------------
extern "C" void kernel_launch(void* const* d_in, const int* in_sizes, int n_in,
                              void* d_out, int out_size, void* d_ws, size_t ws_size,
                              hipStream_t stream) {
  (void)in_sizes; (void)n_in; (void)out_size; (void)ws_size;
  const float* x = (const float*)d_in[0];
  const float* gn_w = (const float*)d_in[1];
  const float* gn_b = (const float*)d_in[2];
  const float* qkv_w = (const float*)d_in[3];
  const float* qkv_b = (const float*)d_in[4];
  const float* proj_w = (const float*)d_in[5];
  const float* proj_b = (const float*)d_in[6];
  float* out = (float*)d_out;

  unsigned short* wsu = (unsigned short*)d_ws;
  unsigned short* xn_t = wsu;                         // [8][1024][512]
  unsigned short* wqkv = xn_t + (size_t)4194304;      // [1536][512]
  unsigned short* wproj = wqkv + (size_t)786432;      // [512][512]
  unsigned short* q_t = wproj + (size_t)262144;       // [64][1024][64]
  unsigned short* k_t = q_t + (size_t)4194304;
  unsigned short* v_t = k_t + (size_t)4194304;        // [64][64][1024]
  unsigned short* h_t = v_t + (size_t)4194304;        // [8][1024][512]

  gn_kernel<<<dim3(256), 256, 0, stream>>>(x, gn_w, gn_b, xn_t);
  cvt_kernel<<<dim3(768), 256, 0, stream>>>(qkv_w, wqkv, 196608);
  cvt_kernel<<<dim3(256), 256, 0, stream>>>(proj_w, wproj, 65536);
  qkv_gemm<<<dim3(768), 256, 0, stream>>>(wqkv, xn_t, qkv_b, q_t, k_t, v_t);
  attn_kernel<<<dim3(1024), 256, 0, stream>>>(q_t, k_t, v_t, h_t);
  proj_gemm<<<dim3(256), 256, 0, stream>>>(wproj, h_t, proj_b, x, out);
}

// Round 8
// 158.044 us; speedup vs baseline: 1.5120x; 1.5120x over previous
//
#include <hip/hip_runtime.h>
#include <math.h>

#define Bn 8
#define Cn 512
#define Tn 1024

typedef __attribute__((ext_vector_type(8))) short bf16x8;
typedef __attribute__((ext_vector_type(4))) float f32x4;

__device__ __forceinline__ unsigned short f2bf(float f) {
  unsigned int u = __builtin_bit_cast(unsigned int, f);
  u = (u + 0x7FFFu + ((u >> 16) & 1u)) >> 16;
  return (unsigned short)u;
}

__device__ __forceinline__ unsigned int cvtpk_bf16(float lo, float hi) {
  unsigned int r;
  asm("v_cvt_pk_bf16_f32 %0, %1, %2" : "=v"(r) : "v"(lo), "v"(hi));
  return r;
}

typedef __attribute__((address_space(1))) const unsigned int GU32;
typedef __attribute__((address_space(3))) unsigned int LU32;
__device__ __forceinline__ void gld16(const unsigned short* g, unsigned short* l) {
  __builtin_amdgcn_global_load_lds((GU32*)g, (LU32*)l, 16, 0, 0);
}

// Stage a 128-row x 64-col bf16 tile into linear LDS [128][64] with
// XOR-swizzled columns: LDS[row][c16] holds G[row][c16 ^ (row&7)] (16B units).
__device__ __forceinline__ void stage128x64(const unsigned short* __restrict__ src,
                                            size_t row_stride, unsigned short* lds, int tid) {
  const int w = tid >> 6;
  const int row = tid >> 3;
  const int sc = (tid & 7) ^ ((tid >> 3) & 7);
#pragma unroll
  for (int c = 0; c < 4; ++c)
    gld16(src + (size_t)(c * 32 + row) * row_stride + sc * 8,
          (unsigned short*)((char*)lds + c * 4096 + w * 1024));
}

// Same for a 64x64 tile (2 calls): LDS[row][u] = G[row][u ^ (row&7)], u in 16B units.
__device__ __forceinline__ void stage64x64(const unsigned short* __restrict__ src,
                                           size_t row_stride, unsigned short* lds, int tid) {
  const int w = tid >> 6;
  const int row = tid >> 3;
  const int sc = (tid & 7) ^ ((tid >> 3) & 7);
#pragma unroll
  for (int c = 0; c < 2; ++c)
    gld16(src + (size_t)(c * 32 + row) * row_stride + sc * 8,
          (unsigned short*)((char*)lds + c * 4096 + w * 1024));
}

// ---------------------------------------------------------------------------
// GroupNorm -> bf16 transposed xn_t [b][t][c]
// ---------------------------------------------------------------------------
__global__ __launch_bounds__(256) void gn_kernel(const float* __restrict__ x,
                                                 const float* __restrict__ gw,
                                                 const float* __restrict__ gb,
                                                 unsigned short* __restrict__ xn_t) {
  const int blk = blockIdx.x;
  const int b = blk >> 5, g = blk & 31;
  const size_t base = ((size_t)b * Cn + (size_t)g * 16) * Tn;
  const float4* __restrict__ xin = (const float4*)(x + base);
  const int tid = threadIdx.x;

  float vv[16][4];
  float sum = 0.f, sq = 0.f;
#pragma unroll
  for (int k = 0; k < 16; ++k) {
    const float4 t4 = xin[tid + (k << 8)];
    vv[k][0] = t4.x; vv[k][1] = t4.y; vv[k][2] = t4.z; vv[k][3] = t4.w;
    sum += t4.x + t4.y + t4.z + t4.w;
    sq += t4.x * t4.x + t4.y * t4.y + t4.z * t4.z + t4.w * t4.w;
  }

  __shared__ float rs[8];
  const int lane = tid & 63, wv = tid >> 6;
#pragma unroll
  for (int off = 32; off > 0; off >>= 1) {
    sum += __shfl_down(sum, off);
    sq += __shfl_down(sq, off);
  }
  if (lane == 0) { rs[wv] = sum; rs[4 + wv] = sq; }
  __syncthreads();
  const float ts = rs[0] + rs[1] + rs[2] + rs[3];
  const float tq = rs[4] + rs[5] + rs[6] + rs[7];
  const float mean = ts * (1.f / 16384.f);
  const float var = tq * (1.f / 16384.f) - mean * mean;
  const float rstd = rsqrtf(var + 1e-5f);

  float aa[16], bb[16];
#pragma unroll
  for (int k = 0; k < 16; ++k) {
    aa[k] = rstd * gw[g * 16 + k];
    bb[k] = gb[g * 16 + k] - mean * aa[k];
  }

#pragma unroll
  for (int j = 0; j < 4; ++j) {
    const int t = tid * 4 + j;
    unsigned int pk[8];
#pragma unroll
    for (int k2 = 0; k2 < 8; ++k2) {
      const unsigned int lo = f2bf(vv[2 * k2][j] * aa[2 * k2] + bb[2 * k2]);
      const unsigned int hi = f2bf(vv[2 * k2 + 1][j] * aa[2 * k2 + 1] + bb[2 * k2 + 1]);
      pk[k2] = lo | (hi << 16);
    }
    unsigned short* dst = xn_t + ((size_t)(b * Tn + t)) * Cn + g * 16;
    *(uint4*)dst = make_uint4(pk[0], pk[1], pk[2], pk[3]);
    *((uint4*)dst + 1) = make_uint4(pk[4], pk[5], pk[6], pk[7]);
  }
}

__global__ __launch_bounds__(256) void cvt_kernel(const float* __restrict__ src,
                                                  unsigned short* __restrict__ dst, int n4) {
  const int i = blockIdx.x * 256 + threadIdx.x;
  if (i < n4) {
    const float4 f = ((const float4*)src)[i];
    uint2 o;
    o.x = (unsigned int)f2bf(f.x) | ((unsigned int)f2bf(f.y) << 16);
    o.y = (unsigned int)f2bf(f.z) | ((unsigned int)f2bf(f.w) << 16);
    ((uint2*)dst)[i] = o;
  }
}

// ---------------------------------------------------------------------------
// QKV GEMM, LDS-staged 128x128 tile, BK=64 double-buffered. Flat grid 768,
// XCD-swizzled: b = id&7. q scaled by 0.125*log2(e) (attn runs in exp2 domain).
// V bounced through LDS for coalesced [c][t] stores.
// ---------------------------------------------------------------------------
__global__ __launch_bounds__(256, 2) void qkv_gemm(const unsigned short* __restrict__ Wb,
                                                   const unsigned short* __restrict__ Xb,
                                                   const float* __restrict__ bias,
                                                   unsigned short* __restrict__ q_t,
                                                   unsigned short* __restrict__ k_t,
                                                   unsigned short* __restrict__ v_t) {
  __shared__ unsigned short As[2][8192];
  __shared__ unsigned short Bs[2][8192];
  const int id = blockIdx.x;
  const int b = id & 7;
  const int inner = id >> 3;           // 0..95
  const int bx = inner % 12, by = inner / 12;
  const int o0 = bx * 128, t0 = by * 128;
  const int tid = threadIdx.x, lane = tid & 63, w = tid >> 6;
  const int wr = w >> 1, wc = w & 1;
  const int ln = lane & 15, g16 = lane >> 4;
  const unsigned short* __restrict__ X = Xb + (size_t)b * Tn * Cn;
  const unsigned short* __restrict__ Wt = Wb + (size_t)o0 * 512;
  const unsigned short* __restrict__ Xt = X + (size_t)t0 * 512;

  f32x4 acc[4][4];
#pragma unroll
  for (int mt = 0; mt < 4; ++mt)
#pragma unroll
    for (int nt = 0; nt < 4; ++nt) acc[mt][nt] = (f32x4){0.f, 0.f, 0.f, 0.f};

  stage128x64(Wt, 512, &As[0][0], tid);
  stage128x64(Xt, 512, &Bs[0][0], tid);
  __syncthreads();

  int buf = 0;
  for (int k0 = 0; k0 < 512; k0 += 64) {
    if (k0 + 64 < 512) {
      stage128x64(Wt + k0 + 64, 512, &As[buf ^ 1][0], tid);
      stage128x64(Xt + k0 + 64, 512, &Bs[buf ^ 1][0], tid);
    }
    const char* Ab = (const char*)&As[buf][0];
    const char* Bb = (const char*)&Bs[buf][0];
    bf16x8 af[4][2], bfr[4][2];
#pragma unroll
    for (int mt = 0; mt < 4; ++mt)
#pragma unroll
      for (int kk = 0; kk < 2; ++kk) {
        const int row = wr * 64 + mt * 16 + ln;
        const int c16 = ((kk << 2) | g16) ^ (ln & 7);
        af[mt][kk] = *(const bf16x8*)(Ab + row * 128 + (c16 << 4));
      }
#pragma unroll
    for (int nt = 0; nt < 4; ++nt)
#pragma unroll
      for (int kk = 0; kk < 2; ++kk) {
        const int row = wc * 64 + nt * 16 + ln;
        const int c16 = ((kk << 2) | g16) ^ (ln & 7);
        bfr[nt][kk] = *(const bf16x8*)(Bb + row * 128 + (c16 << 4));
      }
#pragma unroll
    for (int kk = 0; kk < 2; ++kk)
#pragma unroll
      for (int mt = 0; mt < 4; ++mt)
#pragma unroll
        for (int nt = 0; nt < 4; ++nt)
          acc[mt][nt] =
              __builtin_amdgcn_mfma_f32_16x16x32_bf16(af[mt][kk], bfr[nt][kk], acc[mt][nt], 0, 0, 0);
    __syncthreads();
    buf ^= 1;
  }

  const int o_base = o0 + wr * 64, t_base = t0 + wc * 64;
  const int partw = (o_base >> 6) % 3;          // whole 64-row half is one part
  const int bh = b * 8 + o_base / 192;
  unsigned short (*Vlds)[136] = (unsigned short (*)[136])(&As[0][0]);

  if (partw < 2) {
    unsigned short* qk = (partw == 0 ? q_t : k_t) + (size_t)bh * 65536;
    // q carries 0.125 (attn scale) * log2(e) (exp2-domain softmax)
    const float sc = (partw == 0) ? 0.18033688f : 1.0f;
#pragma unroll
    for (int mt = 0; mt < 4; ++mt) {
      const int ob16 = o_base + mt * 16;
      float bv[4];
#pragma unroll
      for (int r = 0; r < 4; ++r) bv[r] = bias[ob16 + g16 * 4 + r];
#pragma unroll
      for (int nt = 0; nt < 4; ++nt) {
        const int t = t_base + nt * 16 + ln;
        const float v0 = (acc[mt][nt][0] + bv[0]) * sc;
        const float v1 = (acc[mt][nt][1] + bv[1]) * sc;
        const float v2 = (acc[mt][nt][2] + bv[2]) * sc;
        const float v3 = (acc[mt][nt][3] + bv[3]) * sc;
        uint2 pk;
        pk.x = (unsigned int)f2bf(v0) | ((unsigned int)f2bf(v1) << 16);
        pk.y = (unsigned int)f2bf(v2) | ((unsigned int)f2bf(v3) << 16);
        *(uint2*)(qk + (size_t)t * 64 + mt * 16 + g16 * 4) = pk;
      }
    }
  } else {
    // V: write [c][t] tile into LDS (c = mt*16+g16*4+r in [0,64), t local)
#pragma unroll
    for (int mt = 0; mt < 4; ++mt) {
      float bv[4];
#pragma unroll
      for (int r = 0; r < 4; ++r) bv[r] = bias[o_base + mt * 16 + g16 * 4 + r];
#pragma unroll
      for (int nt = 0; nt < 4; ++nt)
#pragma unroll
        for (int r = 0; r < 4; ++r)
          Vlds[mt * 16 + g16 * 4 + r][wc * 64 + nt * 16 + ln] = f2bf(acc[mt][nt][r] + bv[r]);
    }
  }
  __syncthreads();
  const int bxm = bx % 3;     // 1 -> wr=0 half is V; 2 -> wr=1 half is V; 0 -> none
  if (bxm) {
    const int o_first = o0 + (bxm - 1) * 64;    // = 192*hh + 128, so c base = 0
    unsigned short* vdst = v_t + (size_t)(b * 8 + o_first / 192) * 65536;
    const int c = tid >> 2, tseg = (tid & 3) << 5;
    const unsigned short* src = &Vlds[c][tseg];
    unsigned short* p = vdst + (size_t)c * Tn + t0 + tseg;
    const uint4 d0 = *(const uint4*)(src);
    const uint4 d1 = *(const uint4*)(src + 8);
    const uint4 d2 = *(const uint4*)(src + 16);
    const uint4 d3 = *(const uint4*)(src + 24);
    *(uint4*)(p) = d0;
    *(uint4*)(p + 8) = d1;
    *(uint4*)(p + 16) = d2;
    *(uint4*)(p + 24) = d3;
  }
}

// ---------------------------------------------------------------------------
// Flash attention: swapped QK^T (cheap per-lane softmax) + block-level K/V
// LDS staging (global_load_lds, double-buffered, XOR swizzle, 1 barrier/iter).
// 1024 blocks x 4 waves; wave owns 16 t-rows. exp2 domain; defer-max THR=11.
// ---------------------------------------------------------------------------
__global__ __launch_bounds__(256, 3) void attn_kernel(const unsigned short* __restrict__ q_t,
                                                      const unsigned short* __restrict__ k_t,
                                                      const unsigned short* __restrict__ v_t,
                                                      unsigned short* __restrict__ h_t) {
  __shared__ unsigned short Ks[2][4096];   // [64 s][64 c] swizzled
  __shared__ unsigned short Vs[2][4096];   // [64 c][64 s] swizzled
  __shared__ __align__(16) unsigned short P_lds[4][1024];  // per-wave [16 t][64 s]
  const int id = blockIdx.x;
  const int xcd = id & 7, qq = id >> 3;
  const int bh = ((qq >> 4) << 3) | xcd;          // same head -> same XCD
  const int tc = qq & 15;
  const int tid = threadIdx.x, lane = tid & 63, w = tid >> 6;
  const int t_wave = tc * 64 + w * 16;
  const int ln = lane & 15, g16 = lane >> 4, g8 = g16 * 8;
  const unsigned short* __restrict__ qbase = q_t + (size_t)bh * 65536;
  const unsigned short* __restrict__ kbase = k_t + (size_t)bh * 65536;
  const unsigned short* __restrict__ vbase = v_t + (size_t)bh * 65536;
  char* __restrict__ Pb = (char*)P_lds[w];

  // K/V LDS fragment byte offsets: row = f*16 + ln, unit = ((kb<<2)|g16)^(ln&7)
  int koff[4][2];
#pragma unroll
  for (int f = 0; f < 4; ++f)
#pragma unroll
    for (int kb = 0; kb < 2; ++kb)
      koff[f][kb] = (f * 16 + ln) * 128 + ((((kb << 2) | g16) ^ (ln & 7)) << 4);

  // P exchange offsets (swizzle: 16B-unit index ^= (t&7), t = ln)
  int wr_off[4], rd_off[2];
#pragma unroll
  for (int ns = 0; ns < 4; ++ns)
    wr_off[ns] = ln * 128 + ((((ns << 1) | (g16 >> 1)) ^ (ln & 7)) << 4) + ((g16 & 1) << 3);
#pragma unroll
  for (int kb = 0; kb < 2; ++kb)
    rd_off[kb] = ln * 128 + ((((kb << 2) | g16) ^ (ln & 7)) << 4);

  // Q fragment (B-operand): row t = t_wave + ln
  bf16x8 qf[2];
#pragma unroll
  for (int kb = 0; kb < 2; ++kb)
    qf[kb] = *(const bf16x8*)(qbase + (size_t)(t_wave + ln) * 64 + kb * 32 + g8);

  f32x4 o_acc[4];
#pragma unroll
  for (int nc = 0; nc < 4; ++nc) o_acc[nc] = (f32x4){0.f, 0.f, 0.f, 0.f};
  float m_run = -1e30f, l_run = 0.f;

  stage64x64(kbase, 64, &Ks[0][0], tid);
  stage64x64(vbase, 1024, &Vs[0][0], tid);
  __syncthreads();

  int buf = 0;
  for (int st = 0; st < 16; ++st) {
    const int s0 = st << 6;
    if (st < 15) {
      stage64x64(kbase + (size_t)(s0 + 64) * 64, 64, &Ks[buf ^ 1][0], tid);
      stage64x64(vbase + (s0 + 64), 1024, &Vs[buf ^ 1][0], tid);
    }
    const char* Kb = (const char*)&Ks[buf][0];
    const char* Vb = (const char*)&Vs[buf][0];

    // K fragments (A-operand) from LDS
    bf16x8 kf[4][2];
#pragma unroll
    for (int ns = 0; ns < 4; ++ns)
#pragma unroll
      for (int kb = 0; kb < 2; ++kb)
        kf[ns][kb] = *(const bf16x8*)(Kb + koff[ns][kb]);

    f32x4 sacc[4];
#pragma unroll
    for (int ns = 0; ns < 4; ++ns) sacc[ns] = (f32x4){0.f, 0.f, 0.f, 0.f};

    __builtin_amdgcn_s_setprio(1);
#pragma unroll
    for (int kb = 0; kb < 2; ++kb)
#pragma unroll
      for (int ns = 0; ns < 4; ++ns)
        sacc[ns] = __builtin_amdgcn_mfma_f32_16x16x32_bf16(kf[ns][kb], qf[kb], sacc[ns], 0, 0, 0);
    __builtin_amdgcn_s_setprio(0);
    // lane holds S^T[s = s0 + 16ns + 4g16 + r][t = t_wave + ln]

    // V fragments (B-operand) from LDS — issued before softmax
    bf16x8 vf[4][2];
#pragma unroll
    for (int nc = 0; nc < 4; ++nc)
#pragma unroll
      for (int kb = 0; kb < 2; ++kb)
        vf[nc][kb] = *(const bf16x8*)(Vb + koff[nc][kb]);

    // row max: 15 in-lane fmax + 2 shuffles (exp2 domain)
    float m = sacc[0][0];
#pragma unroll
    for (int ns = 0; ns < 4; ++ns)
#pragma unroll
      for (int r = 0; r < 4; ++r) m = fmaxf(m, sacc[ns][r]);
    m = fmaxf(m, __shfl_xor(m, 16));
    m = fmaxf(m, __shfl_xor(m, 32));

    if (__any((m > m_run + 11.f) ? 1 : 0)) {
      const float mnew = fmaxf(m_run, m);
      const float al = __builtin_amdgcn_exp2f(m_run - mnew);
      m_run = mnew;
      l_run *= al;
      float al4[4];
#pragma unroll
      for (int r = 0; r < 4; ++r) al4[r] = __shfl(al, (g16 << 2) + r);
#pragma unroll
      for (int nc = 0; nc < 4; ++nc)
#pragma unroll
        for (int r = 0; r < 4; ++r) o_acc[nc][r] *= al4[r];
    }

    // p = exp2(S - m_run); per-lane sum
    float rsum = 0.f;
#pragma unroll
    for (int ns = 0; ns < 4; ++ns) {
#pragma unroll
      for (int r = 0; r < 4; ++r) {
        sacc[ns][r] = __builtin_amdgcn_exp2f(sacc[ns][r] - m_run);
        rsum += sacc[ns][r];
      }
    }
    rsum += __shfl_xor(rsum, 16);
    rsum += __shfl_xor(rsum, 32);
    l_run += rsum;

    // pack P (bf16) and exchange through swizzled per-wave LDS
#pragma unroll
    for (int ns = 0; ns < 4; ++ns) {
      uint2 pk2;
      pk2.x = cvtpk_bf16(sacc[ns][0], sacc[ns][1]);
      pk2.y = cvtpk_bf16(sacc[ns][2], sacc[ns][3]);
      *(uint2*)(Pb + wr_off[ns]) = pk2;
    }
    bf16x8 pf[2];
#pragma unroll
    for (int kb = 0; kb < 2; ++kb) pf[kb] = *(const bf16x8*)(Pb + rd_off[kb]);

    __builtin_amdgcn_s_setprio(1);
#pragma unroll
    for (int kb = 0; kb < 2; ++kb)
#pragma unroll
      for (int nc = 0; nc < 4; ++nc)
        o_acc[nc] = __builtin_amdgcn_mfma_f32_16x16x32_bf16(pf[kb], vf[nc][kb], o_acc[nc], 0, 0, 0);
    __builtin_amdgcn_s_setprio(0);

    __syncthreads();   // drains staged loads (vmcnt) + protects dbuf reuse
    buf ^= 1;
  }

  // epilogue: O /= l (l lives at lane ln = t_local), store h_t[b][t][hh*64+c]
  const float rl = 1.f / l_run;
  float rl4[4];
#pragma unroll
  for (int r = 0; r < 4; ++r) rl4[r] = __shfl(rl, (g16 << 2) + r);
  const int b = bh >> 3, hh = bh & 7;
  unsigned short* __restrict__ hb = h_t + (size_t)b * Tn * Cn + hh * 64;
#pragma unroll
  for (int nc = 0; nc < 4; ++nc) {
    const int c = nc * 16 + ln;
#pragma unroll
    for (int r = 0; r < 4; ++r) {
      const int t = t_wave + g16 * 4 + r;
      hb[(size_t)t * Cn + c] = f2bf(o_acc[nc][r] * rl4[r]);
    }
  }
}

// ---------------------------------------------------------------------------
// Proj GEMM + bias + residual, LDS-staged. Flat grid 256, XCD-swizzled.
// ---------------------------------------------------------------------------
__global__ __launch_bounds__(256, 2) void proj_gemm(const unsigned short* __restrict__ Wb,
                                                    const unsigned short* __restrict__ Hb,
                                                    const float* __restrict__ pbias,
                                                    const float* __restrict__ x,
                                                    float* __restrict__ out) {
  __shared__ unsigned short As[2][8192];
  __shared__ unsigned short Bs[2][8192];
  const int id = blockIdx.x;
  const int b = id & 7;
  const int inner = id >> 3;            // 0..31
  const int bx = inner & 3, by = inner >> 2;
  const int o0 = bx * 128, t0 = by * 128;
  const int tid = threadIdx.x, lane = tid & 63, w = tid >> 6;
  const int wr = w >> 1, wc = w & 1;
  const int ln = lane & 15, g16 = lane >> 4;
  const unsigned short* __restrict__ H = Hb + (size_t)b * Tn * Cn;
  const unsigned short* __restrict__ Wt = Wb + (size_t)o0 * 512;
  const unsigned short* __restrict__ Ht = H + (size_t)t0 * 512;

  f32x4 acc[4][4];
#pragma unroll
  for (int mt = 0; mt < 4; ++mt)
#pragma unroll
    for (int nt = 0; nt < 4; ++nt) acc[mt][nt] = (f32x4){0.f, 0.f, 0.f, 0.f};

  stage128x64(Wt, 512, &As[0][0], tid);
  stage128x64(Ht, 512, &Bs[0][0], tid);
  __syncthreads();

  int buf = 0;
  for (int k0 = 0; k0 < 512; k0 += 64) {
    if (k0 + 64 < 512) {
      stage128x64(Wt + k0 + 64, 512, &As[buf ^ 1][0], tid);
      stage128x64(Ht + k0 + 64, 512, &Bs[buf ^ 1][0], tid);
    }
    const char* Ab = (const char*)&As[buf][0];
    const char* Bb = (const char*)&Bs[buf][0];
    bf16x8 af[4][2], bfr[4][2];
#pragma unroll
    for (int mt = 0; mt < 4; ++mt)
#pragma unroll
      for (int kk = 0; kk < 2; ++kk) {
        const int row = wr * 64 + mt * 16 + ln;
        const int c16 = ((kk << 2) | g16) ^ (ln & 7);
        af[mt][kk] = *(const bf16x8*)(Ab + row * 128 + (c16 << 4));
      }
#pragma unroll
    for (int nt = 0; nt < 4; ++nt)
#pragma unroll
      for (int kk = 0; kk < 2; ++kk) {
        const int row = wc * 64 + nt * 16 + ln;
        const int c16 = ((kk << 2) | g16) ^ (ln & 7);
        bfr[nt][kk] = *(const bf16x8*)(Bb + row * 128 + (c16 << 4));
      }
#pragma unroll
    for (int kk = 0; kk < 2; ++kk)
#pragma unroll
      for (int mt = 0; mt < 4; ++mt)
#pragma unroll
        for (int nt = 0; nt < 4; ++nt)
          acc[mt][nt] =
              __builtin_amdgcn_mfma_f32_16x16x32_bf16(af[mt][kk], bfr[nt][kk], acc[mt][nt], 0, 0, 0);
    __syncthreads();
    buf ^= 1;
  }

  const int o_base = o0 + wr * 64, t_base = t0 + wc * 64;
#pragma unroll
  for (int mt = 0; mt < 4; ++mt) {
    const int ob = o_base + mt * 16 + g16 * 4;
    float pb[4];
#pragma unroll
    for (int r = 0; r < 4; ++r) pb[r] = pbias[ob + r];
#pragma unroll
    for (int nt = 0; nt < 4; ++nt) {
      const int t = t_base + nt * 16 + ln;
#pragma unroll
      for (int r = 0; r < 4; ++r) {
        const size_t idx = (size_t)b * Cn * Tn + (size_t)(ob + r) * Tn + t;
        out[idx] = acc[mt][nt][r] + pb[r] + x[idx];
      }
    }
  }
}

// ---------------------------------------------------------------------------
extern "C" void kernel_launch(void* const* d_in, const int* in_sizes, int n_in,
                              void* d_out, int out_size, void* d_ws, size_t ws_size,
                              hipStream_t stream) {
  (void)in_sizes; (void)n_in; (void)out_size; (void)ws_size;
  const float* x = (const float*)d_in[0];
  const float* gn_w = (const float*)d_in[1];
  const float* gn_b = (const float*)d_in[2];
  const float* qkv_w = (const float*)d_in[3];
  const float* qkv_b = (const float*)d_in[4];
  const float* proj_w = (const float*)d_in[5];
  const float* proj_b = (const float*)d_in[6];
  float* out = (float*)d_out;

  unsigned short* wsu = (unsigned short*)d_ws;
  unsigned short* xn_t = wsu;                         // [8][1024][512]
  unsigned short* wqkv = xn_t + (size_t)4194304;      // [1536][512]
  unsigned short* wproj = wqkv + (size_t)786432;      // [512][512]
  unsigned short* q_t = wproj + (size_t)262144;       // [64][1024][64]
  unsigned short* k_t = q_t + (size_t)4194304;
  unsigned short* v_t = k_t + (size_t)4194304;        // [64][64][1024]
  unsigned short* h_t = v_t + (size_t)4194304;        // [8][1024][512]

  gn_kernel<<<dim3(256), 256, 0, stream>>>(x, gn_w, gn_b, xn_t);
  cvt_kernel<<<dim3(768), 256, 0, stream>>>(qkv_w, wqkv, 196608);
  cvt_kernel<<<dim3(256), 256, 0, stream>>>(proj_w, wproj, 65536);
  qkv_gemm<<<dim3(768), 256, 0, stream>>>(wqkv, xn_t, qkv_b, q_t, k_t, v_t);
  attn_kernel<<<dim3(1024), 256, 0, stream>>>(q_t, k_t, v_t, h_t);
  proj_gemm<<<dim3(256), 256, 0, stream>>>(wproj, h_t, proj_b, x, out);
}

// Round 10
// 154.805 us; speedup vs baseline: 1.5436x; 1.0209x over previous
//
#include <hip/hip_runtime.h>
#include <math.h>

#define Bn 8
#define Cn 512
#define Tn 1024

typedef __attribute__((ext_vector_type(8))) short bf16x8;
typedef __attribute__((ext_vector_type(4))) float f32x4;

__device__ __forceinline__ unsigned short f2bf(float f) {
  unsigned int u = __builtin_bit_cast(unsigned int, f);
  u = (u + 0x7FFFu + ((u >> 16) & 1u)) >> 16;
  return (unsigned short)u;
}

__device__ __forceinline__ unsigned int cvtpk_bf16(float lo, float hi) {
  unsigned int r;
  asm("v_cvt_pk_bf16_f32 %0, %1, %2" : "=v"(r) : "v"(lo), "v"(hi));
  return r;
}

typedef __attribute__((address_space(1))) const unsigned int GU32;
typedef __attribute__((address_space(3))) unsigned int LU32;
__device__ __forceinline__ void gld16(const unsigned short* g, unsigned short* l) {
  __builtin_amdgcn_global_load_lds((GU32*)g, (LU32*)l, 16, 0, 0);
}

// Stage a 128-row x 64-col bf16 tile into linear LDS [128][64] with
// XOR-swizzled columns: LDS[row][c16] holds G[row][c16 ^ (row&7)] (16B units).
__device__ __forceinline__ void stage128x64(const unsigned short* __restrict__ src,
                                            size_t row_stride, unsigned short* lds, int tid) {
  const int w = tid >> 6;
  const int row = tid >> 3;
  const int sc = (tid & 7) ^ ((tid >> 3) & 7);
#pragma unroll
  for (int c = 0; c < 4; ++c)
    gld16(src + (size_t)(c * 32 + row) * row_stride + sc * 8,
          (unsigned short*)((char*)lds + c * 4096 + w * 1024));
}

// Same for a 64x64 tile (2 calls): LDS[row][u] = G[row][u ^ (row&7)], u in 16B units.
__device__ __forceinline__ void stage64x64(const unsigned short* __restrict__ src,
                                           size_t row_stride, unsigned short* lds, int tid) {
  const int w = tid >> 6;
  const int row = tid >> 3;
  const int sc = (tid & 7) ^ ((tid >> 3) & 7);
#pragma unroll
  for (int c = 0; c < 2; ++c)
    gld16(src + (size_t)(c * 32 + row) * row_stride + sc * 8,
          (unsigned short*)((char*)lds + c * 4096 + w * 1024));
}

// ---------------------------------------------------------------------------
// GroupNorm -> bf16 transposed xn_t [b][t][c]
// ---------------------------------------------------------------------------
__global__ __launch_bounds__(256) void gn_kernel(const float* __restrict__ x,
                                                 const float* __restrict__ gw,
                                                 const float* __restrict__ gb,
                                                 unsigned short* __restrict__ xn_t) {
  const int blk = blockIdx.x;
  const int b = blk >> 5, g = blk & 31;
  const size_t base = ((size_t)b * Cn + (size_t)g * 16) * Tn;
  const float4* __restrict__ xin = (const float4*)(x + base);
  const int tid = threadIdx.x;

  float vv[16][4];
  float sum = 0.f, sq = 0.f;
#pragma unroll
  for (int k = 0; k < 16; ++k) {
    const float4 t4 = xin[tid + (k << 8)];
    vv[k][0] = t4.x; vv[k][1] = t4.y; vv[k][2] = t4.z; vv[k][3] = t4.w;
    sum += t4.x + t4.y + t4.z + t4.w;
    sq += t4.x * t4.x + t4.y * t4.y + t4.z * t4.z + t4.w * t4.w;
  }

  __shared__ float rs[8];
  const int lane = tid & 63, wv = tid >> 6;
#pragma unroll
  for (int off = 32; off > 0; off >>= 1) {
    sum += __shfl_down(sum, off);
    sq += __shfl_down(sq, off);
  }
  if (lane == 0) { rs[wv] = sum; rs[4 + wv] = sq; }
  __syncthreads();
  const float ts = rs[0] + rs[1] + rs[2] + rs[3];
  const float tq = rs[4] + rs[5] + rs[6] + rs[7];
  const float mean = ts * (1.f / 16384.f);
  const float var = tq * (1.f / 16384.f) - mean * mean;
  const float rstd = rsqrtf(var + 1e-5f);

  float aa[16], bb[16];
#pragma unroll
  for (int k = 0; k < 16; ++k) {
    aa[k] = rstd * gw[g * 16 + k];
    bb[k] = gb[g * 16 + k] - mean * aa[k];
  }

#pragma unroll
  for (int j = 0; j < 4; ++j) {
    const int t = tid * 4 + j;
    unsigned int pk[8];
#pragma unroll
    for (int k2 = 0; k2 < 8; ++k2) {
      const unsigned int lo = f2bf(vv[2 * k2][j] * aa[2 * k2] + bb[2 * k2]);
      const unsigned int hi = f2bf(vv[2 * k2 + 1][j] * aa[2 * k2 + 1] + bb[2 * k2 + 1]);
      pk[k2] = lo | (hi << 16);
    }
    unsigned short* dst = xn_t + ((size_t)(b * Tn + t)) * Cn + g * 16;
    *(uint4*)dst = make_uint4(pk[0], pk[1], pk[2], pk[3]);
    *((uint4*)dst + 1) = make_uint4(pk[4], pk[5], pk[6], pk[7]);
  }
}

// fp32 -> bf16 weight convert, both weight tensors in one launch.
// blocks 0..767 -> qkv_w (196608 float4), 768..1023 -> proj_w (65536 float4).
__global__ __launch_bounds__(256) void cvt2_kernel(const float* __restrict__ qkv_w,
                                                   const float* __restrict__ proj_w,
                                                   unsigned short* __restrict__ wqkv,
                                                   unsigned short* __restrict__ wproj) {
  const int blk = blockIdx.x;
  const float* src = (blk < 768) ? qkv_w : proj_w;
  unsigned short* dst = (blk < 768) ? wqkv : wproj;
  const int i = ((blk < 768) ? blk : blk - 768) * 256 + threadIdx.x;
  const float4 f = ((const float4*)src)[i];
  uint2 o;
  o.x = (unsigned int)f2bf(f.x) | ((unsigned int)f2bf(f.y) << 16);
  o.y = (unsigned int)f2bf(f.z) | ((unsigned int)f2bf(f.w) << 16);
  ((uint2*)dst)[i] = o;
}

// ---------------------------------------------------------------------------
// QKV GEMM, LDS-staged 128x128 tile, BK=64 double-buffered. Flat grid 768,
// XCD-swizzled: b = id&7. q scaled by 0.125*log2(e) (attn runs in exp2 domain).
// V bounced through LDS for coalesced [c][t] stores.
// ---------------------------------------------------------------------------
__global__ __launch_bounds__(256, 2) void qkv_gemm(const unsigned short* __restrict__ Wb,
                                                   const unsigned short* __restrict__ Xb,
                                                   const float* __restrict__ bias,
                                                   unsigned short* __restrict__ q_t,
                                                   unsigned short* __restrict__ k_t,
                                                   unsigned short* __restrict__ v_t) {
  __shared__ unsigned short As[2][8192];
  __shared__ unsigned short Bs[2][8192];
  const int id = blockIdx.x;
  const int b = id & 7;
  const int inner = id >> 3;           // 0..95
  const int bx = inner % 12, by = inner / 12;
  const int o0 = bx * 128, t0 = by * 128;
  const int tid = threadIdx.x, lane = tid & 63, w = tid >> 6;
  const int wr = w >> 1, wc = w & 1;
  const int ln = lane & 15, g16 = lane >> 4;
  const unsigned short* __restrict__ X = Xb + (size_t)b * Tn * Cn;
  const unsigned short* __restrict__ Wt = Wb + (size_t)o0 * 512;
  const unsigned short* __restrict__ Xt = X + (size_t)t0 * 512;

  f32x4 acc[4][4];
#pragma unroll
  for (int mt = 0; mt < 4; ++mt)
#pragma unroll
    for (int nt = 0; nt < 4; ++nt) acc[mt][nt] = (f32x4){0.f, 0.f, 0.f, 0.f};

  stage128x64(Wt, 512, &As[0][0], tid);
  stage128x64(Xt, 512, &Bs[0][0], tid);
  __syncthreads();

  int buf = 0;
  for (int k0 = 0; k0 < 512; k0 += 64) {
    if (k0 + 64 < 512) {
      stage128x64(Wt + k0 + 64, 512, &As[buf ^ 1][0], tid);
      stage128x64(Xt + k0 + 64, 512, &Bs[buf ^ 1][0], tid);
    }
    const char* Ab = (const char*)&As[buf][0];
    const char* Bb = (const char*)&Bs[buf][0];
    bf16x8 af[4][2], bfr[4][2];
#pragma unroll
    for (int mt = 0; mt < 4; ++mt)
#pragma unroll
      for (int kk = 0; kk < 2; ++kk) {
        const int row = wr * 64 + mt * 16 + ln;
        const int c16 = ((kk << 2) | g16) ^ (ln & 7);
        af[mt][kk] = *(const bf16x8*)(Ab + row * 128 + (c16 << 4));
      }
#pragma unroll
    for (int nt = 0; nt < 4; ++nt)
#pragma unroll
      for (int kk = 0; kk < 2; ++kk) {
        const int row = wc * 64 + nt * 16 + ln;
        const int c16 = ((kk << 2) | g16) ^ (ln & 7);
        bfr[nt][kk] = *(const bf16x8*)(Bb + row * 128 + (c16 << 4));
      }
#pragma unroll
    for (int kk = 0; kk < 2; ++kk)
#pragma unroll
      for (int mt = 0; mt < 4; ++mt)
#pragma unroll
        for (int nt = 0; nt < 4; ++nt)
          acc[mt][nt] =
              __builtin_amdgcn_mfma_f32_16x16x32_bf16(af[mt][kk], bfr[nt][kk], acc[mt][nt], 0, 0, 0);
    __syncthreads();
    buf ^= 1;
  }

  const int o_base = o0 + wr * 64, t_base = t0 + wc * 64;
  const int partw = (o_base >> 6) % 3;          // whole 64-row half is one part
  const int bh = b * 8 + o_base / 192;
  unsigned short (*Vlds)[136] = (unsigned short (*)[136])(&As[0][0]);

  if (partw < 2) {
    unsigned short* qk = (partw == 0 ? q_t : k_t) + (size_t)bh * 65536;
    // q carries 0.125 (attn scale) * log2(e) (exp2-domain softmax)
    const float sc = (partw == 0) ? 0.18033688f : 1.0f;
#pragma unroll
    for (int mt = 0; mt < 4; ++mt) {
      const int ob16 = o_base + mt * 16;
      float bv[4];
#pragma unroll
      for (int r = 0; r < 4; ++r) bv[r] = bias[ob16 + g16 * 4 + r];
#pragma unroll
      for (int nt = 0; nt < 4; ++nt) {
        const int t = t_base + nt * 16 + ln;
        const float v0 = (acc[mt][nt][0] + bv[0]) * sc;
        const float v1 = (acc[mt][nt][1] + bv[1]) * sc;
        const float v2 = (acc[mt][nt][2] + bv[2]) * sc;
        const float v3 = (acc[mt][nt][3] + bv[3]) * sc;
        uint2 pk;
        pk.x = (unsigned int)f2bf(v0) | ((unsigned int)f2bf(v1) << 16);
        pk.y = (unsigned int)f2bf(v2) | ((unsigned int)f2bf(v3) << 16);
        *(uint2*)(qk + (size_t)t * 64 + mt * 16 + g16 * 4) = pk;
      }
    }
  } else {
    // V: write [c][t] tile into LDS (c = mt*16+g16*4+r in [0,64), t local)
#pragma unroll
    for (int mt = 0; mt < 4; ++mt) {
      float bv[4];
#pragma unroll
      for (int r = 0; r < 4; ++r) bv[r] = bias[o_base + mt * 16 + g16 * 4 + r];
#pragma unroll
      for (int nt = 0; nt < 4; ++nt)
#pragma unroll
        for (int r = 0; r < 4; ++r)
          Vlds[mt * 16 + g16 * 4 + r][wc * 64 + nt * 16 + ln] = f2bf(acc[mt][nt][r] + bv[r]);
    }
  }
  __syncthreads();
  const int bxm = bx % 3;     // 1 -> wr=0 half is V; 2 -> wr=1 half is V; 0 -> none
  if (bxm) {
    const int o_first = o0 + (bxm - 1) * 64;    // = 192*hh + 128, so c base = 0
    unsigned short* vdst = v_t + (size_t)(b * 8 + o_first / 192) * 65536;
    const int c = tid >> 2, tseg = (tid & 3) << 5;
    const unsigned short* src = &Vlds[c][tseg];
    unsigned short* p = vdst + (size_t)c * Tn + t0 + tseg;
    const uint4 d0 = *(const uint4*)(src);
    const uint4 d1 = *(const uint4*)(src + 8);
    const uint4 d2 = *(const uint4*)(src + 16);
    const uint4 d3 = *(const uint4*)(src + 24);
    *(uint4*)(p) = d0;
    *(uint4*)(p + 8) = d1;
    *(uint4*)(p + 16) = d2;
    *(uint4*)(p + 24) = d3;
  }
}

// ---------------------------------------------------------------------------
// Flash attention: swapped QK^T + block K/V LDS staging (dbuf, XOR swizzle).
// 512 blocks x 4 waves; each wave owns 32 t-rows (mt=2) -> K/V LDS reads and
// staging per t-row HALVED vs 16-row waves. exp2 domain; defer-max THR=11.
// ---------------------------------------------------------------------------
__global__ __launch_bounds__(256, 2) void attn_kernel(const unsigned short* __restrict__ q_t,
                                                      const unsigned short* __restrict__ k_t,
                                                      const unsigned short* __restrict__ v_t,
                                                      unsigned short* __restrict__ h_t) {
  __shared__ unsigned short Ks[2][4096];   // [64 s][64 c] swizzled
  __shared__ unsigned short Vs[2][4096];   // [64 c][64 s] swizzled
  __shared__ __align__(16) unsigned short P_lds[4][2048];  // per-wave [32 t][64 s]
  const int id = blockIdx.x;
  const int xcd = id & 7, qq = id >> 3;           // 0..63
  const int b = qq >> 3, tc = qq & 7;
  const int bh = b * 8 + xcd;                     // same head -> same XCD
  const int tid = threadIdx.x, lane = tid & 63, w = tid >> 6;
  const int t_wave = tc * 128 + w * 32;
  const int ln = lane & 15, g16 = lane >> 4, g8 = g16 * 8;
  const unsigned short* __restrict__ qbase = q_t + (size_t)bh * 65536;
  const unsigned short* __restrict__ kbase = k_t + (size_t)bh * 65536;
  const unsigned short* __restrict__ vbase = v_t + (size_t)bh * 65536;
  char* __restrict__ Pb = (char*)P_lds[w];

  // K/V LDS fragment byte offsets: row = f*16 + ln, unit = ((kb<<2)|g16)^(ln&7)
  int koff[4][2];
#pragma unroll
  for (int f = 0; f < 4; ++f)
#pragma unroll
    for (int kb = 0; kb < 2; ++kb)
      koff[f][kb] = (f * 16 + ln) * 128 + ((((kb << 2) | g16) ^ (ln & 7)) << 4);

  // P exchange offsets within a wave's [32][64] region (row = mt*16 + ln)
  int wr_off[4], rd_off[2];
#pragma unroll
  for (int ns = 0; ns < 4; ++ns)
    wr_off[ns] = ln * 128 + ((((ns << 1) | (g16 >> 1)) ^ (ln & 7)) << 4) + ((g16 & 1) << 3);
#pragma unroll
  for (int kb = 0; kb < 2; ++kb)
    rd_off[kb] = ln * 128 + ((((kb << 2) | g16) ^ (ln & 7)) << 4);

  // Q fragments (B-operand): row t = t_wave + mt*16 + ln
  bf16x8 qf[2][2];
#pragma unroll
  for (int mt = 0; mt < 2; ++mt)
#pragma unroll
    for (int kb = 0; kb < 2; ++kb)
      qf[mt][kb] = *(const bf16x8*)(qbase + (size_t)(t_wave + mt * 16 + ln) * 64 + kb * 32 + g8);

  f32x4 o_acc[2][4];
#pragma unroll
  for (int mt = 0; mt < 2; ++mt)
#pragma unroll
    for (int nc = 0; nc < 4; ++nc) o_acc[mt][nc] = (f32x4){0.f, 0.f, 0.f, 0.f};
  float m_run[2] = {-1e30f, -1e30f}, l_run[2] = {0.f, 0.f};

  stage64x64(kbase, 64, &Ks[0][0], tid);
  stage64x64(vbase, 1024, &Vs[0][0], tid);
  __syncthreads();

  int buf = 0;
  for (int st = 0; st < 16; ++st) {
    const int s0 = st << 6;
    if (st < 15) {
      stage64x64(kbase + (size_t)(s0 + 64) * 64, 64, &Ks[buf ^ 1][0], tid);
      stage64x64(vbase + (s0 + 64), 1024, &Vs[buf ^ 1][0], tid);
    }
    const char* Kb = (const char*)&Ks[buf][0];
    const char* Vb = (const char*)&Vs[buf][0];

    // K fragments (A-operand) from LDS — shared by both mt
    bf16x8 kf[4][2];
#pragma unroll
    for (int ns = 0; ns < 4; ++ns)
#pragma unroll
      for (int kb = 0; kb < 2; ++kb)
        kf[ns][kb] = *(const bf16x8*)(Kb + koff[ns][kb]);

    f32x4 sacc[2][4];
#pragma unroll
    for (int mt = 0; mt < 2; ++mt)
#pragma unroll
      for (int ns = 0; ns < 4; ++ns) sacc[mt][ns] = (f32x4){0.f, 0.f, 0.f, 0.f};

    __builtin_amdgcn_s_setprio(1);
#pragma unroll
    for (int kb = 0; kb < 2; ++kb)
#pragma unroll
      for (int ns = 0; ns < 4; ++ns) {
        sacc[0][ns] = __builtin_amdgcn_mfma_f32_16x16x32_bf16(kf[ns][kb], qf[0][kb], sacc[0][ns], 0, 0, 0);
        sacc[1][ns] = __builtin_amdgcn_mfma_f32_16x16x32_bf16(kf[ns][kb], qf[1][kb], sacc[1][ns], 0, 0, 0);
      }
    __builtin_amdgcn_s_setprio(0);
    // lane holds S^T[s = s0 + 16ns + 4g16 + r][t = t_wave + mt*16 + ln]

    // row max per mt: 15 in-lane fmax + 2 shuffles (exp2 domain)
    float m[2];
#pragma unroll
    for (int mt = 0; mt < 2; ++mt) {
      float mm = sacc[mt][0][0];
#pragma unroll
      for (int ns = 0; ns < 4; ++ns)
#pragma unroll
        for (int r = 0; r < 4; ++r) mm = fmaxf(mm, sacc[mt][ns][r]);
      mm = fmaxf(mm, __shfl_xor(mm, 16));
      mm = fmaxf(mm, __shfl_xor(mm, 32));
      m[mt] = mm;
    }

    const bool need = (m[0] > m_run[0] + 11.f) || (m[1] > m_run[1] + 11.f);
    if (__any(need ? 1 : 0)) {
#pragma unroll
      for (int mt = 0; mt < 2; ++mt) {
        const float mnew = fmaxf(m_run[mt], m[mt]);
        const float al = __builtin_amdgcn_exp2f(m_run[mt] - mnew);
        m_run[mt] = mnew;
        l_run[mt] *= al;
        float al4[4];
#pragma unroll
        for (int r = 0; r < 4; ++r) al4[r] = __shfl(al, (g16 << 2) + r);
#pragma unroll
        for (int nc = 0; nc < 4; ++nc)
#pragma unroll
          for (int r = 0; r < 4; ++r) o_acc[mt][nc][r] *= al4[r];
      }
    }

    // p = exp2(S - m_run); per-lane sum; pack to LDS
#pragma unroll
    for (int mt = 0; mt < 2; ++mt) {
      float rsum = 0.f;
#pragma unroll
      for (int ns = 0; ns < 4; ++ns) {
#pragma unroll
        for (int r = 0; r < 4; ++r) {
          sacc[mt][ns][r] = __builtin_amdgcn_exp2f(sacc[mt][ns][r] - m_run[mt]);
          rsum += sacc[mt][ns][r];
        }
      }
      rsum += __shfl_xor(rsum, 16);
      rsum += __shfl_xor(rsum, 32);
      l_run[mt] += rsum;
#pragma unroll
      for (int ns = 0; ns < 4; ++ns) {
        uint2 pk2;
        pk2.x = cvtpk_bf16(sacc[mt][ns][0], sacc[mt][ns][1]);
        pk2.y = cvtpk_bf16(sacc[mt][ns][2], sacc[mt][ns][3]);
        *(uint2*)(Pb + mt * 2048 + wr_off[ns]) = pk2;
      }
    }

    bf16x8 pf[2][2];
#pragma unroll
    for (int mt = 0; mt < 2; ++mt)
#pragma unroll
      for (int kb = 0; kb < 2; ++kb)
        pf[mt][kb] = *(const bf16x8*)(Pb + mt * 2048 + rd_off[kb]);

    // V fragments (B-operand) from LDS — shared by both mt
    bf16x8 vf[4][2];
#pragma unroll
    for (int nc = 0; nc < 4; ++nc)
#pragma unroll
      for (int kb = 0; kb < 2; ++kb)
        vf[nc][kb] = *(const bf16x8*)(Vb + koff[nc][kb]);

    __builtin_amdgcn_s_setprio(1);
#pragma unroll
    for (int kb = 0; kb < 2; ++kb)
#pragma unroll
      for (int nc = 0; nc < 4; ++nc) {
        o_acc[0][nc] = __builtin_amdgcn_mfma_f32_16x16x32_bf16(pf[0][kb], vf[nc][kb], o_acc[0][nc], 0, 0, 0);
        o_acc[1][nc] = __builtin_amdgcn_mfma_f32_16x16x32_bf16(pf[1][kb], vf[nc][kb], o_acc[1][nc], 0, 0, 0);
      }
    __builtin_amdgcn_s_setprio(0);

    __syncthreads();   // drains staged loads (vmcnt) + protects dbuf reuse
    buf ^= 1;
  }

  // epilogue: O /= l (l lives at lane ln = t_local&15), store h_t[b][t][hh*64+c]
  const int bb = bh >> 3, hh = bh & 7;
  unsigned short* __restrict__ hb = h_t + (size_t)bb * Tn * Cn + hh * 64;
#pragma unroll
  for (int mt = 0; mt < 2; ++mt) {
    const float rl = 1.f / l_run[mt];
    float rl4[4];
#pragma unroll
    for (int r = 0; r < 4; ++r) rl4[r] = __shfl(rl, (g16 << 2) + r);
#pragma unroll
    for (int nc = 0; nc < 4; ++nc) {
      const int c = nc * 16 + ln;
#pragma unroll
      for (int r = 0; r < 4; ++r) {
        const int t = t_wave + mt * 16 + g16 * 4 + r;
        hb[(size_t)t * Cn + c] = f2bf(o_acc[mt][nc][r] * rl4[r]);
      }
    }
  }
}

// ---------------------------------------------------------------------------
// Proj GEMM + bias + residual, LDS-staged. Flat grid 256, XCD-swizzled.
// ---------------------------------------------------------------------------
__global__ __launch_bounds__(256, 2) void proj_gemm(const unsigned short* __restrict__ Wb,
                                                    const unsigned short* __restrict__ Hb,
                                                    const float* __restrict__ pbias,
                                                    const float* __restrict__ x,
                                                    float* __restrict__ out) {
  __shared__ unsigned short As[2][8192];
  __shared__ unsigned short Bs[2][8192];
  const int id = blockIdx.x;
  const int b = id & 7;
  const int inner = id >> 3;            // 0..31
  const int bx = inner & 3, by = inner >> 2;
  const int o0 = bx * 128, t0 = by * 128;
  const int tid = threadIdx.x, lane = tid & 63, w = tid >> 6;
  const int wr = w >> 1, wc = w & 1;
  const int ln = lane & 15, g16 = lane >> 4;
  const unsigned short* __restrict__ H = Hb + (size_t)b * Tn * Cn;
  const unsigned short* __restrict__ Wt = Wb + (size_t)o0 * 512;
  const unsigned short* __restrict__ Ht = H + (size_t)t0 * 512;

  f32x4 acc[4][4];
#pragma unroll
  for (int mt = 0; mt < 4; ++mt)
#pragma unroll
    for (int nt = 0; nt < 4; ++nt) acc[mt][nt] = (f32x4){0.f, 0.f, 0.f, 0.f};

  stage128x64(Wt, 512, &As[0][0], tid);
  stage128x64(Ht, 512, &Bs[0][0], tid);
  __syncthreads();

  int buf = 0;
  for (int k0 = 0; k0 < 512; k0 += 64) {
    if (k0 + 64 < 512) {
      stage128x64(Wt + k0 + 64, 512, &As[buf ^ 1][0], tid);
      stage128x64(Ht + k0 + 64, 512, &Bs[buf ^ 1][0], tid);
    }
    const char* Ab = (const char*)&As[buf][0];
    const char* Bb = (const char*)&Bs[buf][0];
    bf16x8 af[4][2], bfr[4][2];
#pragma unroll
    for (int mt = 0; mt < 4; ++mt)
#pragma unroll
      for (int kk = 0; kk < 2; ++kk) {
        const int row = wr * 64 + mt * 16 + ln;
        const int c16 = ((kk << 2) | g16) ^ (ln & 7);
        af[mt][kk] = *(const bf16x8*)(Ab + row * 128 + (c16 << 4));
      }
#pragma unroll
    for (int nt = 0; nt < 4; ++nt)
#pragma unroll
      for (int kk = 0; kk < 2; ++kk) {
        const int row = wc * 64 + nt * 16 + ln;
        const int c16 = ((kk << 2) | g16) ^ (ln & 7);
        bfr[nt][kk] = *(const bf16x8*)(Bb + row * 128 + (c16 << 4));
      }
#pragma unroll
    for (int kk = 0; kk < 2; ++kk)
#pragma unroll
      for (int mt = 0; mt < 4; ++mt)
#pragma unroll
        for (int nt = 0; nt < 4; ++nt)
          acc[mt][nt] =
              __builtin_amdgcn_mfma_f32_16x16x32_bf16(af[mt][kk], bfr[nt][kk], acc[mt][nt], 0, 0, 0);
    __syncthreads();
    buf ^= 1;
  }

  const int o_base = o0 + wr * 64, t_base = t0 + wc * 64;
#pragma unroll
  for (int mt = 0; mt < 4; ++mt) {
    const int ob = o_base + mt * 16 + g16 * 4;
    float pb[4];
#pragma unroll
    for (int r = 0; r < 4; ++r) pb[r] = pbias[ob + r];
#pragma unroll
    for (int nt = 0; nt < 4; ++nt) {
      const int t = t_base + nt * 16 + ln;
#pragma unroll
      for (int r = 0; r < 4; ++r) {
        const size_t idx = (size_t)b * Cn * Tn + (size_t)(ob + r) * Tn + t;
        out[idx] = acc[mt][nt][r] + pb[r] + x[idx];
      }
    }
  }
}

// ---------------------------------------------------------------------------
extern "C" void kernel_launch(void* const* d_in, const int* in_sizes, int n_in,
                              void* d_out, int out_size, void* d_ws, size_t ws_size,
                              hipStream_t stream) {
  (void)in_sizes; (void)n_in; (void)out_size; (void)ws_size;
  const float* x = (const float*)d_in[0];
  const float* gn_w = (const float*)d_in[1];
  const float* gn_b = (const float*)d_in[2];
  const float* qkv_w = (const float*)d_in[3];
  const float* qkv_b = (const float*)d_in[4];
  const float* proj_w = (const float*)d_in[5];
  const float* proj_b = (const float*)d_in[6];
  float* out = (float*)d_out;

  unsigned short* wsu = (unsigned short*)d_ws;
  unsigned short* xn_t = wsu;                         // [8][1024][512]
  unsigned short* wqkv = xn_t + (size_t)4194304;      // [1536][512]
  unsigned short* wproj = wqkv + (size_t)786432;      // [512][512]
  unsigned short* q_t = wproj + (size_t)262144;       // [64][1024][64]
  unsigned short* k_t = q_t + (size_t)4194304;
  unsigned short* v_t = k_t + (size_t)4194304;        // [64][64][1024]
  unsigned short* h_t = v_t + (size_t)4194304;        // [8][1024][512]

  gn_kernel<<<dim3(256), 256, 0, stream>>>(x, gn_w, gn_b, xn_t);
  cvt2_kernel<<<dim3(1024), 256, 0, stream>>>(qkv_w, proj_w, wqkv, wproj);
  qkv_gemm<<<dim3(768), 256, 0, stream>>>(wqkv, xn_t, qkv_b, q_t, k_t, v_t);
  attn_kernel<<<dim3(512), 256, 0, stream>>>(q_t, k_t, v_t, h_t);
  proj_gemm<<<dim3(256), 256, 0, stream>>>(wproj, h_t, proj_b, x, out);
}

// Round 11
// 153.720 us; speedup vs baseline: 1.5545x; 1.0071x over previous
//
#include <hip/hip_runtime.h>
#include <math.h>

#define Bn 8
#define Cn 512
#define Tn 1024

typedef __attribute__((ext_vector_type(8))) short bf16x8;
typedef __attribute__((ext_vector_type(4))) float f32x4;

__device__ __forceinline__ unsigned short f2bf(float f) {
  unsigned int u = __builtin_bit_cast(unsigned int, f);
  u = (u + 0x7FFFu + ((u >> 16) & 1u)) >> 16;
  return (unsigned short)u;
}

__device__ __forceinline__ unsigned int cvtpk_bf16(float lo, float hi) {
  unsigned int r;
  asm("v_cvt_pk_bf16_f32 %0, %1, %2" : "=v"(r) : "v"(lo), "v"(hi));
  return r;
}

typedef __attribute__((address_space(1))) const unsigned int GU32;
typedef __attribute__((address_space(3))) unsigned int LU32;
__device__ __forceinline__ void gld16(const unsigned short* g, unsigned short* l) {
  __builtin_amdgcn_global_load_lds((GU32*)g, (LU32*)l, 16, 0, 0);
}

// Stage a 128-row x 64-col bf16 tile into linear LDS [128][64] with
// XOR-swizzled columns: LDS[row][c16] holds G[row][c16 ^ (row&7)] (16B units).
__device__ __forceinline__ void stage128x64(const unsigned short* __restrict__ src,
                                            size_t row_stride, unsigned short* lds, int tid) {
  const int w = tid >> 6;
  const int row = tid >> 3;
  const int sc = (tid & 7) ^ ((tid >> 3) & 7);
#pragma unroll
  for (int c = 0; c < 4; ++c)
    gld16(src + (size_t)(c * 32 + row) * row_stride + sc * 8,
          (unsigned short*)((char*)lds + c * 4096 + w * 1024));
}

// Same for a 64x64 tile (2 calls, 2 vmem insts/lane): LDS[row][u] = G[row][u ^ (row&7)].
__device__ __forceinline__ void stage64x64(const unsigned short* __restrict__ src,
                                           size_t row_stride, unsigned short* lds, int tid) {
  const int w = tid >> 6;
  const int row = tid >> 3;
  const int sc = (tid & 7) ^ ((tid >> 3) & 7);
#pragma unroll
  for (int c = 0; c < 2; ++c)
    gld16(src + (size_t)(c * 32 + row) * row_stride + sc * 8,
          (unsigned short*)((char*)lds + c * 4096 + w * 1024));
}

// ---------------------------------------------------------------------------
// prep: blocks 0..255 = GroupNorm -> bf16 transposed xn_t [b][t][c];
//       blocks 256..1279 = fp32->bf16 weight convert (qkv_w then proj_w).
// ---------------------------------------------------------------------------
__global__ __launch_bounds__(256) void prep_kernel(const float* __restrict__ x,
                                                   const float* __restrict__ gw,
                                                   const float* __restrict__ gb,
                                                   unsigned short* __restrict__ xn_t,
                                                   const float* __restrict__ qkv_w,
                                                   const float* __restrict__ proj_w,
                                                   unsigned short* __restrict__ wqkv,
                                                   unsigned short* __restrict__ wproj) {
  const int tid = threadIdx.x;
  if (blockIdx.x >= 256) {
    const int blk = blockIdx.x - 256;           // 0..1023
    const float* src = (blk < 768) ? qkv_w : proj_w;
    unsigned short* dst = (blk < 768) ? wqkv : wproj;
    const int i = ((blk < 768) ? blk : blk - 768) * 256 + tid;
    const float4 f = ((const float4*)src)[i];
    uint2 o;
    o.x = (unsigned int)f2bf(f.x) | ((unsigned int)f2bf(f.y) << 16);
    o.y = (unsigned int)f2bf(f.z) | ((unsigned int)f2bf(f.w) << 16);
    ((uint2*)dst)[i] = o;
    return;
  }

  const int blk = blockIdx.x;
  const int b = blk >> 5, g = blk & 31;
  const size_t base = ((size_t)b * Cn + (size_t)g * 16) * Tn;
  const float4* __restrict__ xin = (const float4*)(x + base);

  float vv[16][4];
  float sum = 0.f, sq = 0.f;
#pragma unroll
  for (int k = 0; k < 16; ++k) {
    const float4 t4 = xin[tid + (k << 8)];
    vv[k][0] = t4.x; vv[k][1] = t4.y; vv[k][2] = t4.z; vv[k][3] = t4.w;
    sum += t4.x + t4.y + t4.z + t4.w;
    sq += t4.x * t4.x + t4.y * t4.y + t4.z * t4.z + t4.w * t4.w;
  }

  __shared__ float rs[8];
  const int lane = tid & 63, wv = tid >> 6;
#pragma unroll
  for (int off = 32; off > 0; off >>= 1) {
    sum += __shfl_down(sum, off);
    sq += __shfl_down(sq, off);
  }
  if (lane == 0) { rs[wv] = sum; rs[4 + wv] = sq; }
  __syncthreads();
  const float ts = rs[0] + rs[1] + rs[2] + rs[3];
  const float tq = rs[4] + rs[5] + rs[6] + rs[7];
  const float mean = ts * (1.f / 16384.f);
  const float var = tq * (1.f / 16384.f) - mean * mean;
  const float rstd = rsqrtf(var + 1e-5f);

  float aa[16], bb[16];
#pragma unroll
  for (int k = 0; k < 16; ++k) {
    aa[k] = rstd * gw[g * 16 + k];
    bb[k] = gb[g * 16 + k] - mean * aa[k];
  }

#pragma unroll
  for (int j = 0; j < 4; ++j) {
    const int t = tid * 4 + j;
    unsigned int pk[8];
#pragma unroll
    for (int k2 = 0; k2 < 8; ++k2) {
      const unsigned int lo = f2bf(vv[2 * k2][j] * aa[2 * k2] + bb[2 * k2]);
      const unsigned int hi = f2bf(vv[2 * k2 + 1][j] * aa[2 * k2 + 1] + bb[2 * k2 + 1]);
      pk[k2] = lo | (hi << 16);
    }
    unsigned short* dst = xn_t + ((size_t)(b * Tn + t)) * Cn + g * 16;
    *(uint4*)dst = make_uint4(pk[0], pk[1], pk[2], pk[3]);
    *((uint4*)dst + 1) = make_uint4(pk[4], pk[5], pk[6], pk[7]);
  }
}

// ---------------------------------------------------------------------------
// QKV GEMM, LDS-staged 128x128 tile, BK=64 double-buffered. Flat grid 768,
// XCD-swizzled: b = id&7. q scaled by 0.125*log2(e) (attn runs in exp2 domain).
// V bounced through LDS for coalesced [c][t] stores.
// ---------------------------------------------------------------------------
__global__ __launch_bounds__(256, 2) void qkv_gemm(const unsigned short* __restrict__ Wb,
                                                   const unsigned short* __restrict__ Xb,
                                                   const float* __restrict__ bias,
                                                   unsigned short* __restrict__ q_t,
                                                   unsigned short* __restrict__ k_t,
                                                   unsigned short* __restrict__ v_t) {
  __shared__ unsigned short As[2][8192];
  __shared__ unsigned short Bs[2][8192];
  const int id = blockIdx.x;
  const int b = id & 7;
  const int inner = id >> 3;           // 0..95
  const int bx = inner % 12, by = inner / 12;
  const int o0 = bx * 128, t0 = by * 128;
  const int tid = threadIdx.x, lane = tid & 63, w = tid >> 6;
  const int wr = w >> 1, wc = w & 1;
  const int ln = lane & 15, g16 = lane >> 4;
  const unsigned short* __restrict__ X = Xb + (size_t)b * Tn * Cn;
  const unsigned short* __restrict__ Wt = Wb + (size_t)o0 * 512;
  const unsigned short* __restrict__ Xt = X + (size_t)t0 * 512;

  f32x4 acc[4][4];
#pragma unroll
  for (int mt = 0; mt < 4; ++mt)
#pragma unroll
    for (int nt = 0; nt < 4; ++nt) acc[mt][nt] = (f32x4){0.f, 0.f, 0.f, 0.f};

  stage128x64(Wt, 512, &As[0][0], tid);
  stage128x64(Xt, 512, &Bs[0][0], tid);
  __syncthreads();

  int buf = 0;
  for (int k0 = 0; k0 < 512; k0 += 64) {
    if (k0 + 64 < 512) {
      stage128x64(Wt + k0 + 64, 512, &As[buf ^ 1][0], tid);
      stage128x64(Xt + k0 + 64, 512, &Bs[buf ^ 1][0], tid);
    }
    const char* Ab = (const char*)&As[buf][0];
    const char* Bb = (const char*)&Bs[buf][0];
    bf16x8 af[4][2], bfr[4][2];
#pragma unroll
    for (int mt = 0; mt < 4; ++mt)
#pragma unroll
      for (int kk = 0; kk < 2; ++kk) {
        const int row = wr * 64 + mt * 16 + ln;
        const int c16 = ((kk << 2) | g16) ^ (ln & 7);
        af[mt][kk] = *(const bf16x8*)(Ab + row * 128 + (c16 << 4));
      }
#pragma unroll
    for (int nt = 0; nt < 4; ++nt)
#pragma unroll
      for (int kk = 0; kk < 2; ++kk) {
        const int row = wc * 64 + nt * 16 + ln;
        const int c16 = ((kk << 2) | g16) ^ (ln & 7);
        bfr[nt][kk] = *(const bf16x8*)(Bb + row * 128 + (c16 << 4));
      }
#pragma unroll
    for (int kk = 0; kk < 2; ++kk)
#pragma unroll
      for (int mt = 0; mt < 4; ++mt)
#pragma unroll
        for (int nt = 0; nt < 4; ++nt)
          acc[mt][nt] =
              __builtin_amdgcn_mfma_f32_16x16x32_bf16(af[mt][kk], bfr[nt][kk], acc[mt][nt], 0, 0, 0);
    __syncthreads();
    buf ^= 1;
  }

  const int o_base = o0 + wr * 64, t_base = t0 + wc * 64;
  const int partw = (o_base >> 6) % 3;          // whole 64-row half is one part
  const int bh = b * 8 + o_base / 192;
  unsigned short (*Vlds)[136] = (unsigned short (*)[136])(&As[0][0]);

  if (partw < 2) {
    unsigned short* qk = (partw == 0 ? q_t : k_t) + (size_t)bh * 65536;
    // q carries 0.125 (attn scale) * log2(e) (exp2-domain softmax)
    const float sc = (partw == 0) ? 0.18033688f : 1.0f;
#pragma unroll
    for (int mt = 0; mt < 4; ++mt) {
      const int ob16 = o_base + mt * 16;
      float bv[4];
#pragma unroll
      for (int r = 0; r < 4; ++r) bv[r] = bias[ob16 + g16 * 4 + r];
#pragma unroll
      for (int nt = 0; nt < 4; ++nt) {
        const int t = t_base + nt * 16 + ln;
        const float v0 = (acc[mt][nt][0] + bv[0]) * sc;
        const float v1 = (acc[mt][nt][1] + bv[1]) * sc;
        const float v2 = (acc[mt][nt][2] + bv[2]) * sc;
        const float v3 = (acc[mt][nt][3] + bv[3]) * sc;
        uint2 pk;
        pk.x = (unsigned int)f2bf(v0) | ((unsigned int)f2bf(v1) << 16);
        pk.y = (unsigned int)f2bf(v2) | ((unsigned int)f2bf(v3) << 16);
        *(uint2*)(qk + (size_t)t * 64 + mt * 16 + g16 * 4) = pk;
      }
    }
  } else {
    // V: write [c][t] tile into LDS (c = mt*16+g16*4+r in [0,64), t local)
#pragma unroll
    for (int mt = 0; mt < 4; ++mt) {
      float bv[4];
#pragma unroll
      for (int r = 0; r < 4; ++r) bv[r] = bias[o_base + mt * 16 + g16 * 4 + r];
#pragma unroll
      for (int nt = 0; nt < 4; ++nt)
#pragma unroll
        for (int r = 0; r < 4; ++r)
          Vlds[mt * 16 + g16 * 4 + r][wc * 64 + nt * 16 + ln] = f2bf(acc[mt][nt][r] + bv[r]);
    }
  }
  __syncthreads();
  const int bxm = bx % 3;     // 1 -> wr=0 half is V; 2 -> wr=1 half is V; 0 -> none
  if (bxm) {
    const int o_first = o0 + (bxm - 1) * 64;    // = 192*hh + 128, so c base = 0
    unsigned short* vdst = v_t + (size_t)(b * 8 + o_first / 192) * 65536;
    const int c = tid >> 2, tseg = (tid & 3) << 5;
    const unsigned short* src = &Vlds[c][tseg];
    unsigned short* p = vdst + (size_t)c * Tn + t0 + tseg;
    const uint4 d0 = *(const uint4*)(src);
    const uint4 d1 = *(const uint4*)(src + 8);
    const uint4 d2 = *(const uint4*)(src + 16);
    const uint4 d3 = *(const uint4*)(src + 24);
    *(uint4*)(p) = d0;
    *(uint4*)(p + 8) = d1;
    *(uint4*)(p + 16) = d2;
    *(uint4*)(p + 24) = d3;
  }
}

// ---------------------------------------------------------------------------
// Flash attention: swapped QK^T + 3-slot K/V LDS pipeline staged 2 tiles
// ahead with COUNTED vmcnt (T3/T4): prefetch for tile st+2 stays in flight
// across the barrier; tile st+1 (issued a full iteration earlier) is drained.
// 512 blocks x 4 waves; wave owns 32 t-rows. exp2 domain; defer-max THR=11.
// ---------------------------------------------------------------------------
__global__ __launch_bounds__(256, 2) void attn_kernel(const unsigned short* __restrict__ q_t,
                                                      const unsigned short* __restrict__ k_t,
                                                      const unsigned short* __restrict__ v_t,
                                                      unsigned short* __restrict__ h_t) {
  __shared__ unsigned short Ks[3][4096];   // [64 s][64 c] swizzled, 3-slot
  __shared__ unsigned short Vs[3][4096];   // [64 c][64 s] swizzled, 3-slot
  __shared__ __align__(16) unsigned short P_lds[4][2048];  // per-wave [32 t][64 s]
  const int id = blockIdx.x;
  const int xcd = id & 7, qq = id >> 3;           // 0..63
  const int b = qq >> 3, tc = qq & 7;
  const int bh = b * 8 + xcd;                     // same head -> same XCD
  const int tid = threadIdx.x, lane = tid & 63, w = tid >> 6;
  const int t_wave = tc * 128 + w * 32;
  const int ln = lane & 15, g16 = lane >> 4, g8 = g16 * 8;
  const unsigned short* __restrict__ qbase = q_t + (size_t)bh * 65536;
  const unsigned short* __restrict__ kbase = k_t + (size_t)bh * 65536;
  const unsigned short* __restrict__ vbase = v_t + (size_t)bh * 65536;
  char* __restrict__ Pb = (char*)P_lds[w];

  // K/V LDS fragment byte offsets: row = f*16 + ln, unit = ((kb<<2)|g16)^(ln&7)
  int koff[4][2];
#pragma unroll
  for (int f = 0; f < 4; ++f)
#pragma unroll
    for (int kb = 0; kb < 2; ++kb)
      koff[f][kb] = (f * 16 + ln) * 128 + ((((kb << 2) | g16) ^ (ln & 7)) << 4);

  // P exchange offsets within a wave's [32][64] region (row = mt*16 + ln)
  int wr_off[4], rd_off[2];
#pragma unroll
  for (int ns = 0; ns < 4; ++ns)
    wr_off[ns] = ln * 128 + ((((ns << 1) | (g16 >> 1)) ^ (ln & 7)) << 4) + ((g16 & 1) << 3);
#pragma unroll
  for (int kb = 0; kb < 2; ++kb)
    rd_off[kb] = ln * 128 + ((((kb << 2) | g16) ^ (ln & 7)) << 4);

  // Q fragments (B-operand) first: they age out of vmcnt before staging loads.
  bf16x8 qf[2][2];
#pragma unroll
  for (int mt = 0; mt < 2; ++mt)
#pragma unroll
    for (int kb = 0; kb < 2; ++kb)
      qf[mt][kb] = *(const bf16x8*)(qbase + (size_t)(t_wave + mt * 16 + ln) * 64 + kb * 32 + g8);

  f32x4 o_acc[2][4];
#pragma unroll
  for (int mt = 0; mt < 2; ++mt)
#pragma unroll
    for (int nc = 0; nc < 4; ++nc) o_acc[mt][nc] = (f32x4){0.f, 0.f, 0.f, 0.f};
  float m_run[2] = {-1e30f, -1e30f}, l_run[2] = {0.f, 0.f};

  // prologue: tiles 0 and 1 in flight (4 vmem insts each); drain tile 0 only.
  stage64x64(kbase, 64, &Ks[0][0], tid);
  stage64x64(vbase, 1024, &Vs[0][0], tid);
  stage64x64(kbase + (size_t)64 * 64, 64, &Ks[1][0], tid);
  stage64x64(vbase + 64, 1024, &Vs[1][0], tid);
  asm volatile("s_waitcnt vmcnt(4)" ::: "memory");
  __builtin_amdgcn_s_barrier();
  __builtin_amdgcn_sched_barrier(0);

  int cur = 0;
  for (int st = 0; st < 16; ++st) {
    const int s2 = (cur >= 1) ? cur - 1 : cur + 2;   // (cur+2)%3
    if (st < 14) {
      const int s0n = (st + 2) << 6;
      stage64x64(kbase + (size_t)s0n * 64, 64, &Ks[s2][0], tid);
      stage64x64(vbase + s0n, 1024, &Vs[s2][0], tid);
    }
    const char* Kb = (const char*)&Ks[cur][0];
    const char* Vb = (const char*)&Vs[cur][0];

    // K fragments (A-operand) from LDS — shared by both mt
    bf16x8 kf[4][2];
#pragma unroll
    for (int ns = 0; ns < 4; ++ns)
#pragma unroll
      for (int kb = 0; kb < 2; ++kb)
        kf[ns][kb] = *(const bf16x8*)(Kb + koff[ns][kb]);

    f32x4 sacc[2][4];
#pragma unroll
    for (int mt = 0; mt < 2; ++mt)
#pragma unroll
      for (int ns = 0; ns < 4; ++ns) sacc[mt][ns] = (f32x4){0.f, 0.f, 0.f, 0.f};

    __builtin_amdgcn_s_setprio(1);
#pragma unroll
    for (int kb = 0; kb < 2; ++kb)
#pragma unroll
      for (int ns = 0; ns < 4; ++ns) {
        sacc[0][ns] = __builtin_amdgcn_mfma_f32_16x16x32_bf16(kf[ns][kb], qf[0][kb], sacc[0][ns], 0, 0, 0);
        sacc[1][ns] = __builtin_amdgcn_mfma_f32_16x16x32_bf16(kf[ns][kb], qf[1][kb], sacc[1][ns], 0, 0, 0);
      }
    __builtin_amdgcn_s_setprio(0);
    // lane holds S^T[s = s0 + 16ns + 4g16 + r][t = t_wave + mt*16 + ln]

    // row max per mt: 15 in-lane fmax + 2 shuffles (exp2 domain)
    float m[2];
#pragma unroll
    for (int mt = 0; mt < 2; ++mt) {
      float mm = sacc[mt][0][0];
#pragma unroll
      for (int ns = 0; ns < 4; ++ns)
#pragma unroll
        for (int r = 0; r < 4; ++r) mm = fmaxf(mm, sacc[mt][ns][r]);
      mm = fmaxf(mm, __shfl_xor(mm, 16));
      mm = fmaxf(mm, __shfl_xor(mm, 32));
      m[mt] = mm;
    }

    const bool need = (m[0] > m_run[0] + 11.f) || (m[1] > m_run[1] + 11.f);
    if (__any(need ? 1 : 0)) {
#pragma unroll
      for (int mt = 0; mt < 2; ++mt) {
        const float mnew = fmaxf(m_run[mt], m[mt]);
        const float al = __builtin_amdgcn_exp2f(m_run[mt] - mnew);
        m_run[mt] = mnew;
        l_run[mt] *= al;
        float al4[4];
#pragma unroll
        for (int r = 0; r < 4; ++r) al4[r] = __shfl(al, (g16 << 2) + r);
#pragma unroll
        for (int nc = 0; nc < 4; ++nc)
#pragma unroll
          for (int r = 0; r < 4; ++r) o_acc[mt][nc][r] *= al4[r];
      }
    }

    // p = exp2(S - m_run); per-lane sum; pack to LDS
#pragma unroll
    for (int mt = 0; mt < 2; ++mt) {
      float rsum = 0.f;
#pragma unroll
      for (int ns = 0; ns < 4; ++ns) {
#pragma unroll
        for (int r = 0; r < 4; ++r) {
          sacc[mt][ns][r] = __builtin_amdgcn_exp2f(sacc[mt][ns][r] - m_run[mt]);
          rsum += sacc[mt][ns][r];
        }
      }
      rsum += __shfl_xor(rsum, 16);
      rsum += __shfl_xor(rsum, 32);
      l_run[mt] += rsum;
#pragma unroll
      for (int ns = 0; ns < 4; ++ns) {
        uint2 pk2;
        pk2.x = cvtpk_bf16(sacc[mt][ns][0], sacc[mt][ns][1]);
        pk2.y = cvtpk_bf16(sacc[mt][ns][2], sacc[mt][ns][3]);
        *(uint2*)(Pb + mt * 2048 + wr_off[ns]) = pk2;
      }
    }

    bf16x8 pf[2][2];
#pragma unroll
    for (int mt = 0; mt < 2; ++mt)
#pragma unroll
      for (int kb = 0; kb < 2; ++kb)
        pf[mt][kb] = *(const bf16x8*)(Pb + mt * 2048 + rd_off[kb]);

    // V fragments (B-operand) from LDS — shared by both mt
    bf16x8 vf[4][2];
#pragma unroll
    for (int nc = 0; nc < 4; ++nc)
#pragma unroll
      for (int kb = 0; kb < 2; ++kb)
        vf[nc][kb] = *(const bf16x8*)(Vb + koff[nc][kb]);

    __builtin_amdgcn_s_setprio(1);
#pragma unroll
    for (int kb = 0; kb < 2; ++kb)
#pragma unroll
      for (int nc = 0; nc < 4; ++nc) {
        o_acc[0][nc] = __builtin_amdgcn_mfma_f32_16x16x32_bf16(pf[0][kb], vf[nc][kb], o_acc[0][nc], 0, 0, 0);
        o_acc[1][nc] = __builtin_amdgcn_mfma_f32_16x16x32_bf16(pf[1][kb], vf[nc][kb], o_acc[1][nc], 0, 0, 0);
      }
    __builtin_amdgcn_s_setprio(0);

    // counted drain: tile st+1 (older) must be complete; tile st+2's 4 loads
    // may stay in flight. Last two iters have no new issue -> full drain.
    if (st < 14) {
      asm volatile("s_waitcnt vmcnt(4)" ::: "memory");
    } else {
      asm volatile("s_waitcnt vmcnt(0)" ::: "memory");
    }
    __builtin_amdgcn_s_barrier();
    __builtin_amdgcn_sched_barrier(0);
    cur = (cur >= 2) ? 0 : cur + 1;
  }

  // epilogue: O /= l (l lives at lane ln = t_local&15), store h_t[b][t][hh*64+c]
  const int bb = bh >> 3, hh = bh & 7;
  unsigned short* __restrict__ hb = h_t + (size_t)bb * Tn * Cn + hh * 64;
#pragma unroll
  for (int mt = 0; mt < 2; ++mt) {
    const float rl = 1.f / l_run[mt];
    float rl4[4];
#pragma unroll
    for (int r = 0; r < 4; ++r) rl4[r] = __shfl(rl, (g16 << 2) + r);
#pragma unroll
    for (int nc = 0; nc < 4; ++nc) {
      const int c = nc * 16 + ln;
#pragma unroll
      for (int r = 0; r < 4; ++r) {
        const int t = t_wave + mt * 16 + g16 * 4 + r;
        hb[(size_t)t * Cn + c] = f2bf(o_acc[mt][nc][r] * rl4[r]);
      }
    }
  }
}

// ---------------------------------------------------------------------------
// Proj GEMM + bias + residual, LDS-staged. Flat grid 256, XCD-swizzled.
// ---------------------------------------------------------------------------
__global__ __launch_bounds__(256, 2) void proj_gemm(const unsigned short* __restrict__ Wb,
                                                    const unsigned short* __restrict__ Hb,
                                                    const float* __restrict__ pbias,
                                                    const float* __restrict__ x,
                                                    float* __restrict__ out) {
  __shared__ unsigned short As[2][8192];
  __shared__ unsigned short Bs[2][8192];
  const int id = blockIdx.x;
  const int b = id & 7;
  const int inner = id >> 3;            // 0..31
  const int bx = inner & 3, by = inner >> 2;
  const int o0 = bx * 128, t0 = by * 128;
  const int tid = threadIdx.x, lane = tid & 63, w = tid >> 6;
  const int wr = w >> 1, wc = w & 1;
  const int ln = lane & 15, g16 = lane >> 4;
  const unsigned short* __restrict__ H = Hb + (size_t)b * Tn * Cn;
  const unsigned short* __restrict__ Wt = Wb + (size_t)o0 * 512;
  const unsigned short* __restrict__ Ht = H + (size_t)t0 * 512;

  f32x4 acc[4][4];
#pragma unroll
  for (int mt = 0; mt < 4; ++mt)
#pragma unroll
    for (int nt = 0; nt < 4; ++nt) acc[mt][nt] = (f32x4){0.f, 0.f, 0.f, 0.f};

  stage128x64(Wt, 512, &As[0][0], tid);
  stage128x64(Ht, 512, &Bs[0][0], tid);
  __syncthreads();

  int buf = 0;
  for (int k0 = 0; k0 < 512; k0 += 64) {
    if (k0 + 64 < 512) {
      stage128x64(Wt + k0 + 64, 512, &As[buf ^ 1][0], tid);
      stage128x64(Ht + k0 + 64, 512, &Bs[buf ^ 1][0], tid);
    }
    const char* Ab = (const char*)&As[buf][0];
    const char* Bb = (const char*)&Bs[buf][0];
    bf16x8 af[4][2], bfr[4][2];
#pragma unroll
    for (int mt = 0; mt < 4; ++mt)
#pragma unroll
      for (int kk = 0; kk < 2; ++kk) {
        const int row = wr * 64 + mt * 16 + ln;
        const int c16 = ((kk << 2) | g16) ^ (ln & 7);
        af[mt][kk] = *(const bf16x8*)(Ab + row * 128 + (c16 << 4));
      }
#pragma unroll
    for (int nt = 0; nt < 4; ++nt)
#pragma unroll
      for (int kk = 0; kk < 2; ++kk) {
        const int row = wc * 64 + nt * 16 + ln;
        const int c16 = ((kk << 2) | g16) ^ (ln & 7);
        bfr[nt][kk] = *(const bf16x8*)(Bb + row * 128 + (c16 << 4));
      }
#pragma unroll
    for (int kk = 0; kk < 2; ++kk)
#pragma unroll
      for (int mt = 0; mt < 4; ++mt)
#pragma unroll
        for (int nt = 0; nt < 4; ++nt)
          acc[mt][nt] =
              __builtin_amdgcn_mfma_f32_16x16x32_bf16(af[mt][kk], bfr[nt][kk], acc[mt][nt], 0, 0, 0);
    __syncthreads();
    buf ^= 1;
  }

  const int o_base = o0 + wr * 64, t_base = t0 + wc * 64;
#pragma unroll
  for (int mt = 0; mt < 4; ++mt) {
    const int ob = o_base + mt * 16 + g16 * 4;
    float pb[4];
#pragma unroll
    for (int r = 0; r < 4; ++r) pb[r] = pbias[ob + r];
#pragma unroll
    for (int nt = 0; nt < 4; ++nt) {
      const int t = t_base + nt * 16 + ln;
#pragma unroll
      for (int r = 0; r < 4; ++r) {
        const size_t idx = (size_t)b * Cn * Tn + (size_t)(ob + r) * Tn + t;
        out[idx] = acc[mt][nt][r] + pb[r] + x[idx];
      }
    }
  }
}

// ---------------------------------------------------------------------------
extern "C" void kernel_launch(void* const* d_in, const int* in_sizes, int n_in,
                              void* d_out, int out_size, void* d_ws, size_t ws_size,
                              hipStream_t stream) {
  (void)in_sizes; (void)n_in; (void)out_size; (void)ws_size;
  const float* x = (const float*)d_in[0];
  const float* gn_w = (const float*)d_in[1];
  const float* gn_b = (const float*)d_in[2];
  const float* qkv_w = (const float*)d_in[3];
  const float* qkv_b = (const float*)d_in[4];
  const float* proj_w = (const float*)d_in[5];
  const float* proj_b = (const float*)d_in[6];
  float* out = (float*)d_out;

  unsigned short* wsu = (unsigned short*)d_ws;
  unsigned short* xn_t = wsu;                         // [8][1024][512]
  unsigned short* wqkv = xn_t + (size_t)4194304;      // [1536][512]
  unsigned short* wproj = wqkv + (size_t)786432;      // [512][512]
  unsigned short* q_t = wproj + (size_t)262144;       // [64][1024][64]
  unsigned short* k_t = q_t + (size_t)4194304;
  unsigned short* v_t = k_t + (size_t)4194304;        // [64][64][1024]
  unsigned short* h_t = v_t + (size_t)4194304;        // [8][1024][512]

  prep_kernel<<<dim3(1280), 256, 0, stream>>>(x, gn_w, gn_b, xn_t, qkv_w, proj_w, wqkv, wproj);
  qkv_gemm<<<dim3(768), 256, 0, stream>>>(wqkv, xn_t, qkv_b, q_t, k_t, v_t);
  attn_kernel<<<dim3(512), 256, 0, stream>>>(q_t, k_t, v_t, h_t);
  proj_gemm<<<dim3(256), 256, 0, stream>>>(wproj, h_t, proj_b, x, out);
}